// Round 1
// baseline (1753.717 us; speedup 1.0000x reference)
//
#include <hip/hip_runtime.h>
#include <hip/hip_bf16.h>

// Problem constants (fixed by the reference setup)
#define NNODES   50000
#define NGRAPHS  64
#define INDIM    1024
#define HIDC     64      // channels per head
#define HEADS1   4
#define F1       (HEADS1*HIDC)   // 256
#define NEG_SLOPE 0.2f

// ---------------------------------------------------------------------------
// Workspace layout (4-byte words). All float4-accessed buffers 16B-aligned.
// h2 / hfin alias the (dead-after-agg1) h1 region.
#define WS_COUNTS   0                    // int[50000]
#define WS_POOLED   50000                // float[4096]
#define WS_GCNT     54096                // float[64]
#define WS_ZEROLEN  54160                // words to zero
#define WS_INDPTR   54208                // int[50001]
#define WS_CURSOR   104256               // int[50000]
#define WS_CSRSRC   154304               // int[850000]
#define WS_ALS1     1004352              // float[200000]
#define WS_ALD1     1204352              // float[200000]
#define WS_ALS2     1404352              // float[50000]
#define WS_ALD2     1454400              // float[50000]
#define WS_H1       1504448              // float[12,800,000]
#define WS_X2       14304448             // float[12,800,000]
#define WS_H2       WS_H1                // alias: float[3,200,000]
#define WS_HFIN     (WS_H1 + 3200000)    // alias: float[3,200,000]

// ---------------------------------------------------------------------------
__global__ void zero_kernel(float* p, int n) {
    int i = blockIdx.x * blockDim.x + threadIdx.x;
    if (i < n) p[i] = 0.0f;
}

// histogram of dst
__global__ void hist_kernel(const int* __restrict__ dst, int* __restrict__ counts, int E) {
    int i = blockIdx.x * blockDim.x + threadIdx.x;
    if (i < E) atomicAdd(&counts[dst[i]], 1);
}

// single-block exclusive scan: indptr[0..N], cursor[i] = exclusive prefix
__global__ __launch_bounds__(1024) void scan_kernel(const int* __restrict__ counts,
                                                    int* __restrict__ indptr,
                                                    int* __restrict__ cursor, int N) {
    __shared__ int sm[1024];
    __shared__ int carry_s;
    if (threadIdx.x == 0) { carry_s = 0; indptr[0] = 0; }
    __syncthreads();
    for (int base = 0; base < N; base += 1024) {
        int i = base + (int)threadIdx.x;
        int v = (i < N) ? counts[i] : 0;
        sm[threadIdx.x] = v;
        __syncthreads();
        for (int off = 1; off < 1024; off <<= 1) {
            int t = (threadIdx.x >= (unsigned)off) ? sm[threadIdx.x - off] : 0;
            __syncthreads();
            sm[threadIdx.x] += t;
            __syncthreads();
        }
        int carry = carry_s;
        if (i < N) {
            int incl = sm[threadIdx.x] + carry;
            indptr[i + 1] = incl;
            cursor[i] = incl - v;
        }
        __syncthreads();
        if (threadIdx.x == 1023) carry_s = carry + sm[1023];
        __syncthreads();
    }
}

// scatter src node ids into CSR slots (order within a segment is arbitrary; softmax is order-robust)
__global__ void fill_kernel(const int* __restrict__ src, const int* __restrict__ dst,
                            int* __restrict__ cursor, int* __restrict__ csr_src, int E) {
    int i = blockIdx.x * blockDim.x + threadIdx.x;
    if (i < E) {
        int d = dst[i];
        int pos = atomicAdd(&cursor[d], 1);
        csr_src[pos] = src[i];
    }
}

// ---------------------------------------------------------------------------
// fp32 tiled GEMM: C[M,N] = A[M,K] @ B[K,N].  64x64 tile, BK=32, 256 thr, 4x4/thr.
// Requires: N % 64 == 0, K % 32 == 0 (true here); M guarded.
__global__ __launch_bounds__(256) void gemm_tiled(const float* __restrict__ A,
                                                  const float* __restrict__ B,
                                                  float* __restrict__ C,
                                                  int M, int N, int K) {
    __shared__ __align__(16) float As[32][64];   // [k][m] (A transposed in LDS)
    __shared__ __align__(16) float Bs[32][64];   // [k][n]
    int tid = threadIdx.x;
    int tx = tid & 15, ty = tid >> 4;
    int m0 = blockIdx.x * 64, n0 = blockIdx.y * 64;
    float acc[4][4] = {};

    for (int k0 = 0; k0 < K; k0 += 32) {
        #pragma unroll
        for (int l = 0; l < 2; ++l) {
            int lin = tid + l * 256;         // 0..511, each covers 4 floats
            int ar = lin >> 3;               // 0..63
            int ac = (lin & 7) << 2;         // 0,4,..,28
            float4 f = make_float4(0.f, 0.f, 0.f, 0.f);
            if (m0 + ar < M)
                f = *(const float4*)&A[(size_t)(m0 + ar) * K + k0 + ac];
            As[ac + 0][ar] = f.x; As[ac + 1][ar] = f.y;
            As[ac + 2][ar] = f.z; As[ac + 3][ar] = f.w;
        }
        #pragma unroll
        for (int l = 0; l < 2; ++l) {
            int lin = tid + l * 256;
            int br = lin >> 4;               // 0..31
            int bc = (lin & 15) << 2;        // 0..60
            *(float4*)&Bs[br][bc] = *(const float4*)&B[(size_t)(k0 + br) * N + n0 + bc];
        }
        __syncthreads();
        #pragma unroll
        for (int kk = 0; kk < 32; ++kk) {
            float4 a = *(const float4*)&As[kk][ty * 4];
            float4 b = *(const float4*)&Bs[kk][tx * 4];
            float av[4] = {a.x, a.y, a.z, a.w};
            float bv[4] = {b.x, b.y, b.z, b.w};
            #pragma unroll
            for (int i = 0; i < 4; ++i)
                #pragma unroll
                for (int j = 0; j < 4; ++j)
                    acc[i][j] += av[i] * bv[j];
        }
        __syncthreads();
    }
    #pragma unroll
    for (int i = 0; i < 4; ++i) {
        int m = m0 + ty * 4 + i;
        if (m < M) {
            float4 o = make_float4(acc[i][0], acc[i][1], acc[i][2], acc[i][3]);
            *(float4*)&C[(size_t)m * N + n0 + tx * 4] = o;
        }
    }
}

// ---------------------------------------------------------------------------
__device__ __forceinline__ float wave_reduce_sum(float v) {
    #pragma unroll
    for (int off = 32; off > 0; off >>= 1) v += __shfl_xor(v, off, 64);
    return v;
}

// al_s[n,h] = <h[n,h,:], asrc[h,:]>, al_d likewise. One wave per node; 4 nodes/block.
__global__ __launch_bounds__(256) void att_kernel(const float* __restrict__ h,
                                                  const float* __restrict__ asrc,
                                                  const float* __restrict__ adst,
                                                  float* __restrict__ al_s,
                                                  float* __restrict__ al_d,
                                                  int N, int H) {
    int lane = threadIdx.x & 63;
    int n = blockIdx.x * 4 + (threadIdx.x >> 6);
    if (n >= N) return;
    for (int hh = 0; hh < H; ++hh) {
        float hv = h[(size_t)n * H * 64 + hh * 64 + lane];
        float s = wave_reduce_sum(hv * asrc[hh * 64 + lane]);
        float d = wave_reduce_sum(hv * adst[hh * 64 + lane]);
        if (lane == 0) {
            al_s[n * H + hh] = s;
            al_d[n * H + hh] = d;
        }
    }
}

// Gather-based softmax aggregation + bias + ELU.
// H*64 threads per node; 256-thread blocks => 1 node/block (H=4) or 4 nodes/block (H=1).
template<int H>
__global__ __launch_bounds__(256) void agg_kernel(const float* __restrict__ h,
                                                  const float* __restrict__ al_s,
                                                  const float* __restrict__ al_d,
                                                  const int* __restrict__ indptr,
                                                  const int* __restrict__ csr_src,
                                                  const float* __restrict__ bias,
                                                  float* __restrict__ out, int N) {
    const int TPN = H * 64;
    int n = blockIdx.x * (256 / TPN) + (int)(threadIdx.x / TPN);
    int t = threadIdx.x % TPN;
    int hh = t >> 6;
    if (n >= N) return;
    int beg = indptr[n], end = indptr[n + 1];
    float ald = al_d[n * H + hh];

    float mx = -1e30f;
    for (int i = beg; i < end; ++i) {
        int s = csr_src[i];
        float e = al_s[s * H + hh] + ald;
        e = (e > 0.f) ? e : NEG_SLOPE * e;
        mx = fmaxf(mx, e);
    }
    float den = 0.f, acc = 0.f;
    for (int i = beg; i < end; ++i) {
        int s = csr_src[i];
        float e = al_s[s * H + hh] + ald;
        e = (e > 0.f) ? e : NEG_SLOPE * e;
        float w = __expf(e - mx);
        den += w;
        acc += w * h[(size_t)s * TPN + t];
    }
    float o = acc / den + bias[t];
    o = (o > 0.f) ? o : (__expf(o) - 1.0f);   // ELU
    out[(size_t)n * TPN + t] = o;
}

// atomic mean-pool accumulation
__global__ void pool_kernel(const float* __restrict__ hfin, const int* __restrict__ batch,
                            float* __restrict__ pooled, float* __restrict__ gcnt, int N) {
    int gid = blockIdx.x * blockDim.x + threadIdx.x;
    int n = gid >> 6, c = gid & 63;
    if (n >= N) return;
    int g = batch[n];
    atomicAdd(&pooled[g * 64 + c], hfin[(size_t)n * 64 + c]);
    if (c == 0) atomicAdd(&gcnt[g], 1.0f);
}

// out[g,j] = (pooled[g,:]/cnt[g]) @ fc_w[:,j] + fc_b[j]
__global__ void final_kernel(const float* __restrict__ pooled, const float* __restrict__ gcnt,
                             const float* __restrict__ fc_w, const float* __restrict__ fc_b,
                             float* __restrict__ out) {
    int tid = threadIdx.x;
    if (tid >= NGRAPHS * 2) return;
    int g = tid >> 1, j = tid & 1;
    float cnt = fmaxf(gcnt[g], 1.0f);
    float s = 0.f;
    for (int c = 0; c < 64; ++c) s += pooled[g * 64 + c] * fc_w[c * 2 + j];
    out[g * 2 + j] = s / cnt + fc_b[j];
}

// ---------------------------------------------------------------------------
extern "C" void kernel_launch(void* const* d_in, const int* in_sizes, int n_in,
                              void* d_out, int out_size, void* d_ws, size_t ws_size,
                              hipStream_t stream) {
    const float* x      = (const float*)d_in[0];
    const int*   ei     = (const int*)d_in[1];
    const int*   batch  = (const int*)d_in[2];
    const float* W1     = (const float*)d_in[3];
    const float* asrc1  = (const float*)d_in[4];
    const float* adst1  = (const float*)d_in[5];
    const float* b1     = (const float*)d_in[6];
    const float* W2     = (const float*)d_in[7];
    const float* asrc2  = (const float*)d_in[8];
    const float* adst2  = (const float*)d_in[9];
    const float* b2     = (const float*)d_in[10];
    const float* fc_w   = (const float*)d_in[11];
    const float* fc_b   = (const float*)d_in[12];
    float* out          = (float*)d_out;

    const int N = in_sizes[2];          // 50000
    const int E = in_sizes[1] / 2;      // 850000
    const int* src = ei;
    const int* dst = ei + E;

    float* ws = (float*)d_ws;
    int*   counts  = (int*)(ws + WS_COUNTS);
    float* pooled  = ws + WS_POOLED;
    float* gcnt    = ws + WS_GCNT;
    int*   indptr  = (int*)(ws + WS_INDPTR);
    int*   cursor  = (int*)(ws + WS_CURSOR);
    int*   csr_src = (int*)(ws + WS_CSRSRC);
    float* al_s1   = ws + WS_ALS1;
    float* al_d1   = ws + WS_ALD1;
    float* al_s2   = ws + WS_ALS2;
    float* al_d2   = ws + WS_ALD2;
    float* h1      = ws + WS_H1;
    float* x2      = ws + WS_X2;
    float* h2      = ws + WS_H2;     // aliases h1 (h1 dead after agg1)
    float* hfin    = ws + WS_HFIN;   // aliases h1 tail

    // 1. zero counts + pooled + gcnt
    zero_kernel<<<(WS_ZEROLEN + 255) / 256, 256, 0, stream>>>(ws, WS_ZEROLEN);
    // 2. CSR build (by dst)
    hist_kernel<<<(E + 255) / 256, 256, 0, stream>>>(dst, counts, E);
    scan_kernel<<<1, 1024, 0, stream>>>(counts, indptr, cursor, N);
    fill_kernel<<<(E + 255) / 256, 256, 0, stream>>>(src, dst, cursor, csr_src, E);
    // 3. layer 1: h1 = x @ W1   [50000,1024]x[1024,256]
    gemm_tiled<<<dim3((N + 63) / 64, F1 / 64), 256, 0, stream>>>(x, W1, h1, N, F1, INDIM);
    // 4. attention logits
    att_kernel<<<(N + 3) / 4, 256, 0, stream>>>(h1, asrc1, adst1, al_s1, al_d1, N, HEADS1);
    // 5. softmax-aggregate + bias + ELU -> x2
    agg_kernel<HEADS1><<<N, 256, 0, stream>>>(h1, al_s1, al_d1, indptr, csr_src, b1, x2, N);
    // 6. layer 2: h2 = x2 @ W2  [50000,256]x[256,64]
    gemm_tiled<<<dim3((N + 63) / 64, 1), 256, 0, stream>>>(x2, W2, h2, N, HIDC, F1);
    // 7. attention logits layer 2
    att_kernel<<<(N + 3) / 4, 256, 0, stream>>>(h2, asrc2, adst2, al_s2, al_d2, N, 1);
    // 8. aggregate + bias + ELU -> hfin
    agg_kernel<1><<<(N + 3) / 4, 256, 0, stream>>>(h2, al_s2, al_d2, indptr, csr_src, b2, hfin, N);
    // 9. mean pool + FC
    pool_kernel<<<((N * 64) + 255) / 256, 256, 0, stream>>>(hfin, batch, pooled, gcnt, N);
    final_kernel<<<1, 128, 0, stream>>>(pooled, gcnt, fc_w, fc_b, out);
}

// Round 2
// 1511.494 us; speedup vs baseline: 1.1603x; 1.1603x over previous
//
#include <hip/hip_runtime.h>
#include <hip/hip_bf16.h>

// Problem constants (fixed by the reference setup)
#define NNODES   50000
#define NGRAPHS  64
#define INDIM    1024
#define HIDC     64      // channels per head
#define HEADS1   4
#define F1       (HEADS1*HIDC)   // 256
#define NEG_SLOPE 0.2f

// ---------------------------------------------------------------------------
// Workspace layout (4-byte words). All float4-accessed buffers 16B-aligned.
// h2 / hfin alias the (dead-after-agg1) h1 region.
#define WS_COUNTS   0                    // int[50000]
#define WS_POOLED   50000                // float[4096]
#define WS_GCNT     54096                // float[64]
#define WS_ZEROLEN  54160                // words to zero
#define WS_INDPTR   54208                // int[50001]
#define WS_CURSOR   104256               // int[50000]
#define WS_CSRSRC   154304               // int[850000]
#define WS_ALS1     1004352              // float[200000]
#define WS_ALD1     1204352              // float[200000]
#define WS_ALS2     1404352              // float[50000]
#define WS_ALD2     1454400              // float[50000]
#define WS_H1       1504448              // float[12,800,000]
#define WS_X2       14304448             // float[12,800,000]
#define WS_BP       27104448             // ushort[262144] = 131072 words (packed bf16 W1)
#define WS_H2       WS_H1                // alias: float[3,200,000]
#define WS_HFIN     (WS_H1 + 3200000)    // alias: float[3,200,000]

typedef __attribute__((ext_vector_type(8))) short bf16x8;
typedef __attribute__((ext_vector_type(4))) float f32x4;

__device__ __forceinline__ ushort f2bf(float f) {
    union { float f; uint u; } v; v.f = f;
    uint r = v.u + 0x7fff + ((v.u >> 16) & 1);   // round-to-nearest-even
    return (ushort)(r >> 16);
}

// ---------------------------------------------------------------------------
__global__ void zero_kernel(float* p, int n) {
    int i = blockIdx.x * blockDim.x + threadIdx.x;
    if (i < n) p[i] = 0.0f;
}

// histogram of dst
__global__ void hist_kernel(const int* __restrict__ dst, int* __restrict__ counts, int E) {
    int i = blockIdx.x * blockDim.x + threadIdx.x;
    if (i < E) atomicAdd(&counts[dst[i]], 1);
}

// single-block exclusive scan: indptr[0..N], cursor[i] = exclusive prefix
__global__ __launch_bounds__(1024) void scan_kernel(const int* __restrict__ counts,
                                                    int* __restrict__ indptr,
                                                    int* __restrict__ cursor, int N) {
    __shared__ int sm[1024];
    __shared__ int carry_s;
    if (threadIdx.x == 0) { carry_s = 0; indptr[0] = 0; }
    __syncthreads();
    for (int base = 0; base < N; base += 1024) {
        int i = base + (int)threadIdx.x;
        int v = (i < N) ? counts[i] : 0;
        sm[threadIdx.x] = v;
        __syncthreads();
        for (int off = 1; off < 1024; off <<= 1) {
            int t = (threadIdx.x >= (unsigned)off) ? sm[threadIdx.x - off] : 0;
            __syncthreads();
            sm[threadIdx.x] += t;
            __syncthreads();
        }
        int carry = carry_s;
        if (i < N) {
            int incl = sm[threadIdx.x] + carry;
            indptr[i + 1] = incl;
            cursor[i] = incl - v;
        }
        __syncthreads();
        if (threadIdx.x == 1023) carry_s = carry + sm[1023];
        __syncthreads();
    }
}

// scatter src node ids into CSR slots (order within a segment is arbitrary; softmax is order-robust)
__global__ void fill_kernel(const int* __restrict__ src, const int* __restrict__ dst,
                            int* __restrict__ cursor, int* __restrict__ csr_src, int E) {
    int i = blockIdx.x * blockDim.x + threadIdx.x;
    if (i < E) {
        int d = dst[i];
        int pos = atomicAdd(&cursor[d], 1);
        csr_src[pos] = src[i];
    }
}

// ---------------------------------------------------------------------------
// Pack W1 [1024,256] fp32 into bf16 MFMA-B fragment order:
// Bp[((ntile*32 + kchunk)*64 + lane)*8 + j] = bf16(W[k][n]),
//   k = kchunk*32 + (lane>>4)*8 + j,  n = ntile*16 + (lane&15)
__global__ void pack_w1(const float* __restrict__ W, ushort* __restrict__ Bp) {
    int o = blockIdx.x * blockDim.x + threadIdx.x;   // 0 .. 262143
    int j = o & 7;
    int lane = (o >> 3) & 63;
    int kchunk = (o >> 9) & 31;
    int ntile = o >> 14;
    int k = kchunk * 32 + (lane >> 4) * 8 + j;
    int n = ntile * 16 + (lane & 15);
    Bp[o] = f2bf(W[k * 256 + n]);
}

// ---------------------------------------------------------------------------
// bf16 MFMA GEMM, layer 1: C[M,256] = A[M,1024] @ W1.  A is fp32, converted to
// bf16 during LDS staging. 128x128 tile, 4 waves (2x2), 16x16x32 MFMA.
// LDS A-tile uses XOR swizzle (chunk idx = m*4 + (c ^ ((m>>1)&3))) so frag
// ds_read_b128 is 2-way-conflict only (free per m136).
__global__ __launch_bounds__(256) void gemm1_mfma(const float* __restrict__ A,
                                                  const ushort* __restrict__ Bp,
                                                  float* __restrict__ C, int M) {
    __shared__ __align__(16) ushort Atile[128 * 32];   // 8 KB
    const int K = 1024, N = 256;
    int tid = threadIdx.x;
    int lane = tid & 63;
    int w = tid >> 6;
    int wm = w >> 1, wn = w & 1;
    int m0 = blockIdx.x * 128;
    int n0 = blockIdx.y * 128;

    // staging precompute: 4 slots/thread, slot = (m row 0..127, half-chunk 0..7)
    const float* srow[4];
    int soff[4];
    #pragma unroll
    for (int l = 0; l < 4; ++l) {
        int slot = l * 256 + tid;
        int m = slot >> 3, hc = slot & 7;
        int c = hc >> 1;
        int row = m0 + m; if (row >= M) row = M - 1;   // clamp; masked at store
        srow[l] = A + (size_t)row * K + hc * 4;
        soff[l] = (m * 4 + (c ^ ((m >> 1) & 3))) * 8 + (hc & 1) * 4;
    }
    // A-frag LDS offsets (ushort index): row r, chunk c=lane>>4, swizzled
    int afrag_off[4];
    #pragma unroll
    for (int mt = 0; mt < 4; ++mt) {
        int r = wm * 64 + mt * 16 + (lane & 15);
        int cq = lane >> 4;
        afrag_off[mt] = (r * 4 + (cq ^ ((r >> 1) & 3))) * 8;
    }
    // B frag global bases (fragment-packed, coalesced 1KB/wave loads from L2)
    const ushort* bbase[4];
    #pragma unroll
    for (int nt = 0; nt < 4; ++nt) {
        int ntile = blockIdx.y * 8 + wn * 4 + nt;
        bbase[nt] = Bp + ((size_t)(ntile * 32) * 64 + lane) * 8;
    }

    f32x4 acc[4][4] = {};

    for (int k0 = 0; k0 < K; k0 += 32) {
        // stage A tile (fp32 -> bf16)
        #pragma unroll
        for (int l = 0; l < 4; ++l) {
            float4 v = *(const float4*)(srow[l] + k0);
            ushort4 b;
            b.x = f2bf(v.x); b.y = f2bf(v.y); b.z = f2bf(v.z); b.w = f2bf(v.w);
            *(ushort4*)&Atile[soff[l]] = b;
        }
        // B fragments straight from global (hits L2; Bp is 512 KB)
        int kc = k0 >> 5;
        bf16x8 bfr[4];
        #pragma unroll
        for (int nt = 0; nt < 4; ++nt)
            bfr[nt] = *(const bf16x8*)(bbase[nt] + (size_t)kc * 64 * 8);
        __syncthreads();
        bf16x8 afr[4];
        #pragma unroll
        for (int mt = 0; mt < 4; ++mt)
            afr[mt] = *(const bf16x8*)&Atile[afrag_off[mt]];
        #pragma unroll
        for (int mt = 0; mt < 4; ++mt)
            #pragma unroll
            for (int nt = 0; nt < 4; ++nt)
                acc[mt][nt] = __builtin_amdgcn_mfma_f32_16x16x32_bf16(afr[mt], bfr[nt], acc[mt][nt], 0, 0, 0);
        __syncthreads();
    }
    // epilogue: C/D layout col=lane&15, row=(lane>>4)*4+r
    #pragma unroll
    for (int mt = 0; mt < 4; ++mt) {
        #pragma unroll
        for (int nt = 0; nt < 4; ++nt) {
            int col = n0 + wn * 64 + nt * 16 + (lane & 15);
            #pragma unroll
            for (int r = 0; r < 4; ++r) {
                int row = m0 + wm * 64 + mt * 16 + (lane >> 4) * 4 + r;
                if (row < M) C[(size_t)row * N + col] = acc[mt][nt][r];
            }
        }
    }
}

// ---------------------------------------------------------------------------
// fp32 tiled GEMM (kept for layer 2): C[M,N] = A[M,K] @ B[K,N].
__global__ __launch_bounds__(256) void gemm_tiled(const float* __restrict__ A,
                                                  const float* __restrict__ B,
                                                  float* __restrict__ C,
                                                  int M, int N, int K) {
    __shared__ __align__(16) float As[32][64];   // [k][m]
    __shared__ __align__(16) float Bs[32][64];   // [k][n]
    int tid = threadIdx.x;
    int tx = tid & 15, ty = tid >> 4;
    int m0 = blockIdx.x * 64, n0 = blockIdx.y * 64;
    float acc[4][4] = {};

    for (int k0 = 0; k0 < K; k0 += 32) {
        #pragma unroll
        for (int l = 0; l < 2; ++l) {
            int lin = tid + l * 256;
            int ar = lin >> 3;
            int ac = (lin & 7) << 2;
            float4 f = make_float4(0.f, 0.f, 0.f, 0.f);
            if (m0 + ar < M)
                f = *(const float4*)&A[(size_t)(m0 + ar) * K + k0 + ac];
            As[ac + 0][ar] = f.x; As[ac + 1][ar] = f.y;
            As[ac + 2][ar] = f.z; As[ac + 3][ar] = f.w;
        }
        #pragma unroll
        for (int l = 0; l < 2; ++l) {
            int lin = tid + l * 256;
            int br = lin >> 4;
            int bc = (lin & 15) << 2;
            *(float4*)&Bs[br][bc] = *(const float4*)&B[(size_t)(k0 + br) * N + n0 + bc];
        }
        __syncthreads();
        #pragma unroll
        for (int kk = 0; kk < 32; ++kk) {
            float4 a = *(const float4*)&As[kk][ty * 4];
            float4 b = *(const float4*)&Bs[kk][tx * 4];
            float av[4] = {a.x, a.y, a.z, a.w};
            float bv[4] = {b.x, b.y, b.z, b.w};
            #pragma unroll
            for (int i = 0; i < 4; ++i)
                #pragma unroll
                for (int j = 0; j < 4; ++j)
                    acc[i][j] += av[i] * bv[j];
        }
        __syncthreads();
    }
    #pragma unroll
    for (int i = 0; i < 4; ++i) {
        int m = m0 + ty * 4 + i;
        if (m < M) {
            float4 o = make_float4(acc[i][0], acc[i][1], acc[i][2], acc[i][3]);
            *(float4*)&C[(size_t)m * N + n0 + tx * 4] = o;
        }
    }
}

// ---------------------------------------------------------------------------
__device__ __forceinline__ float wave_reduce_sum(float v) {
    #pragma unroll
    for (int off = 32; off > 0; off >>= 1) v += __shfl_xor(v, off, 64);
    return v;
}

// al_s[n,h] = <h[n,h,:], asrc[h,:]>, al_d likewise. One wave per node; 4 nodes/block.
__global__ __launch_bounds__(256) void att_kernel(const float* __restrict__ h,
                                                  const float* __restrict__ asrc,
                                                  const float* __restrict__ adst,
                                                  float* __restrict__ al_s,
                                                  float* __restrict__ al_d,
                                                  int N, int H) {
    int lane = threadIdx.x & 63;
    int n = blockIdx.x * 4 + (threadIdx.x >> 6);
    if (n >= N) return;
    for (int hh = 0; hh < H; ++hh) {
        float hv = h[(size_t)n * H * 64 + hh * 64 + lane];
        float s = wave_reduce_sum(hv * asrc[hh * 64 + lane]);
        float d = wave_reduce_sum(hv * adst[hh * 64 + lane]);
        if (lane == 0) {
            al_s[n * H + hh] = s;
            al_d[n * H + hh] = d;
        }
    }
}

// Gather-based softmax aggregation + bias + ELU.
template<int H>
__global__ __launch_bounds__(256) void agg_kernel(const float* __restrict__ h,
                                                  const float* __restrict__ al_s,
                                                  const float* __restrict__ al_d,
                                                  const int* __restrict__ indptr,
                                                  const int* __restrict__ csr_src,
                                                  const float* __restrict__ bias,
                                                  float* __restrict__ out, int N) {
    const int TPN = H * 64;
    int n = blockIdx.x * (256 / TPN) + (int)(threadIdx.x / TPN);
    int t = threadIdx.x % TPN;
    int hh = t >> 6;
    if (n >= N) return;
    int beg = indptr[n], end = indptr[n + 1];
    float ald = al_d[n * H + hh];

    float mx = -1e30f;
    for (int i = beg; i < end; ++i) {
        int s = csr_src[i];
        float e = al_s[s * H + hh] + ald;
        e = (e > 0.f) ? e : NEG_SLOPE * e;
        mx = fmaxf(mx, e);
    }
    float den = 0.f, acc = 0.f;
    for (int i = beg; i < end; ++i) {
        int s = csr_src[i];
        float e = al_s[s * H + hh] + ald;
        e = (e > 0.f) ? e : NEG_SLOPE * e;
        float w = __expf(e - mx);
        den += w;
        acc += w * h[(size_t)s * TPN + t];
    }
    float o = acc / den + bias[t];
    o = (o > 0.f) ? o : (__expf(o) - 1.0f);   // ELU
    out[(size_t)n * TPN + t] = o;
}

// atomic mean-pool accumulation
__global__ void pool_kernel(const float* __restrict__ hfin, const int* __restrict__ batch,
                            float* __restrict__ pooled, float* __restrict__ gcnt, int N) {
    int gid = blockIdx.x * blockDim.x + threadIdx.x;
    int n = gid >> 6, c = gid & 63;
    if (n >= N) return;
    int g = batch[n];
    atomicAdd(&pooled[g * 64 + c], hfin[(size_t)n * 64 + c]);
    if (c == 0) atomicAdd(&gcnt[g], 1.0f);
}

// out[g,j] = (pooled[g,:]/cnt[g]) @ fc_w[:,j] + fc_b[j]
__global__ void final_kernel(const float* __restrict__ pooled, const float* __restrict__ gcnt,
                             const float* __restrict__ fc_w, const float* __restrict__ fc_b,
                             float* __restrict__ out) {
    int tid = threadIdx.x;
    if (tid >= NGRAPHS * 2) return;
    int g = tid >> 1, j = tid & 1;
    float cnt = fmaxf(gcnt[g], 1.0f);
    float s = 0.f;
    for (int c = 0; c < 64; ++c) s += pooled[g * 64 + c] * fc_w[c * 2 + j];
    out[g * 2 + j] = s / cnt + fc_b[j];
}

// ---------------------------------------------------------------------------
extern "C" void kernel_launch(void* const* d_in, const int* in_sizes, int n_in,
                              void* d_out, int out_size, void* d_ws, size_t ws_size,
                              hipStream_t stream) {
    const float* x      = (const float*)d_in[0];
    const int*   ei     = (const int*)d_in[1];
    const int*   batch  = (const int*)d_in[2];
    const float* W1     = (const float*)d_in[3];
    const float* asrc1  = (const float*)d_in[4];
    const float* adst1  = (const float*)d_in[5];
    const float* b1     = (const float*)d_in[6];
    const float* W2     = (const float*)d_in[7];
    const float* asrc2  = (const float*)d_in[8];
    const float* adst2  = (const float*)d_in[9];
    const float* b2     = (const float*)d_in[10];
    const float* fc_w   = (const float*)d_in[11];
    const float* fc_b   = (const float*)d_in[12];
    float* out          = (float*)d_out;

    const int N = in_sizes[2];          // 50000
    const int E = in_sizes[1] / 2;      // 850000
    const int* src = ei;
    const int* dst = ei + E;

    float* ws = (float*)d_ws;
    int*    counts  = (int*)(ws + WS_COUNTS);
    float*  pooled  = ws + WS_POOLED;
    float*  gcnt    = ws + WS_GCNT;
    int*    indptr  = (int*)(ws + WS_INDPTR);
    int*    cursor  = (int*)(ws + WS_CURSOR);
    int*    csr_src = (int*)(ws + WS_CSRSRC);
    float*  al_s1   = ws + WS_ALS1;
    float*  al_d1   = ws + WS_ALD1;
    float*  al_s2   = ws + WS_ALS2;
    float*  al_d2   = ws + WS_ALD2;
    float*  h1      = ws + WS_H1;
    float*  x2      = ws + WS_X2;
    ushort* bp      = (ushort*)(ws + WS_BP);
    float*  h2      = ws + WS_H2;     // aliases h1 (h1 dead after agg1)
    float*  hfin    = ws + WS_HFIN;   // aliases h1 tail

    // 1. zero counts + pooled + gcnt; pack W1 to bf16 fragment order
    zero_kernel<<<(WS_ZEROLEN + 255) / 256, 256, 0, stream>>>(ws, WS_ZEROLEN);
    pack_w1<<<(INDIM * F1) / 256, 256, 0, stream>>>(W1, bp);
    // 2. CSR build (by dst)
    hist_kernel<<<(E + 255) / 256, 256, 0, stream>>>(dst, counts, E);
    scan_kernel<<<1, 1024, 0, stream>>>(counts, indptr, cursor, N);
    fill_kernel<<<(E + 255) / 256, 256, 0, stream>>>(src, dst, cursor, csr_src, E);
    // 3. layer 1: h1 = x @ W1  via bf16 MFMA  [50000,1024]x[1024,256]
    gemm1_mfma<<<dim3((N + 127) / 128, F1 / 128), 256, 0, stream>>>(x, bp, h1, N);
    // 4. attention logits
    att_kernel<<<(N + 3) / 4, 256, 0, stream>>>(h1, asrc1, adst1, al_s1, al_d1, N, HEADS1);
    // 5. softmax-aggregate + bias + ELU -> x2
    agg_kernel<HEADS1><<<N, 256, 0, stream>>>(h1, al_s1, al_d1, indptr, csr_src, b1, x2, N);
    // 6. layer 2: h2 = x2 @ W2  [50000,256]x[256,64]  (fp32, small)
    gemm_tiled<<<dim3((N + 63) / 64, 1), 256, 0, stream>>>(x2, W2, h2, N, HIDC, F1);
    // 7. attention logits layer 2
    att_kernel<<<(N + 3) / 4, 256, 0, stream>>>(h2, asrc2, adst2, al_s2, al_d2, N, 1);
    // 8. aggregate + bias + ELU -> hfin
    agg_kernel<1><<<(N + 3) / 4, 256, 0, stream>>>(h2, al_s2, al_d2, indptr, csr_src, b2, hfin, N);
    // 9. mean pool + FC
    pool_kernel<<<((N * 64) + 255) / 256, 256, 0, stream>>>(hfin, batch, pooled, gcnt, N);
    final_kernel<<<1, 128, 0, stream>>>(pooled, gcnt, fc_w, fc_b, out);
}

// Round 3
// 1304.752 us; speedup vs baseline: 1.3441x; 1.1585x over previous
//
#include <hip/hip_runtime.h>
#include <hip/hip_bf16.h>

// Problem constants (fixed by the reference setup)
#define NNODES   50000
#define NGRAPHS  64
#define INDIM    1024
#define HIDC     64      // channels per head
#define HEADS1   4
#define F1       (HEADS1*HIDC)   // 256
#define NEG_SLOPE 0.2f

// ---------------------------------------------------------------------------
// Workspace layout (4-byte words). All float4-accessed buffers 16B-aligned.
#define WS_COUNTS   0                    // int[50000]
#define WS_POOLED   50000                // float[4096]
#define WS_GCNT     54096                // float[64]
#define WS_ZEROLEN  54160                // words to zero
#define WS_INDPTR   54208                // int[50001]
#define WS_CURSOR   104256               // int[50000]
#define WS_CSRSRC   154304               // int[850000]
#define WS_ALS1     1004352              // float[200000]
#define WS_ALD1     1204352              // float[200000]
#define WS_ALS2     1404352              // float[50000]
#define WS_ALD2     1454400              // float[50000]
#define WS_H1       1504448              // float[12,800,000]
#define WS_X2       14304448             // float[12,800,000]
#define WS_BP       27104448             // ushort[262144] = 131072 words (packed bf16 W1)
#define WS_CSRDST   27235520             // int[850000]
#define WS_W1E      28085520             // float[3,400,000]  (w2e aliases this, dead by then)
#define WS_BSUM     31485520             // int[64]
#define WS_H2       WS_H1                // alias: float[3,200,000]
#define WS_HFIN     (WS_H1 + 3200000)    // alias: float[3,200,000]

typedef __attribute__((ext_vector_type(8))) short bf16x8;
typedef __attribute__((ext_vector_type(4))) float f32x4;

__device__ __forceinline__ ushort f2bf(float f) {
    union { float f; uint u; } v; v.f = f;
    uint r = v.u + 0x7fff + ((v.u >> 16) & 1);   // round-to-nearest-even
    return (ushort)(r >> 16);
}

// ---------------------------------------------------------------------------
__global__ void zero_kernel(float* p, int n) {
    int i = blockIdx.x * blockDim.x + threadIdx.x;
    if (i < n) p[i] = 0.0f;
}

// histogram of dst
__global__ void hist_kernel(const int* __restrict__ dst, int* __restrict__ counts, int E) {
    int i = blockIdx.x * blockDim.x + threadIdx.x;
    if (i < E) atomicAdd(&counts[dst[i]], 1);
}

// --- 3-kernel multi-block scan -------------------------------------------
// scan1: per-block inclusive scan of counts into indptr[i+1]; blocksum[b].
__global__ __launch_bounds__(1024) void scan1_kernel(const int* __restrict__ counts,
                                                     int* __restrict__ indptr,
                                                     int* __restrict__ bsum, int N) {
    __shared__ int sm[1024];
    int b = blockIdx.x;
    int i = b * 1024 + (int)threadIdx.x;
    int v = (i < N) ? counts[i] : 0;
    sm[threadIdx.x] = v;
    __syncthreads();
    for (int off = 1; off < 1024; off <<= 1) {
        int t = (threadIdx.x >= (unsigned)off) ? sm[threadIdx.x - off] : 0;
        __syncthreads();
        sm[threadIdx.x] += t;
        __syncthreads();
    }
    if (i < N) indptr[i + 1] = sm[threadIdx.x];
    if (threadIdx.x == 1023) bsum[b] = sm[1023];
}

// scan2: single wave, exclusive scan of <=64 block sums in-place.
__global__ void scan2_kernel(int* __restrict__ bsum, int nb) {
    int lane = threadIdx.x;
    int v = (lane < nb) ? bsum[lane] : 0;
    int orig = v;
    #pragma unroll
    for (int off = 1; off < 64; off <<= 1) {
        int t = __shfl_up(v, off, 64);
        if (lane >= off) v += t;
    }
    if (lane < nb) bsum[lane] = v - orig;   // exclusive
}

// scan3: add block offsets; produce cursor; indptr[0]=0.
__global__ __launch_bounds__(1024) void scan3_kernel(const int* __restrict__ counts,
                                                     int* __restrict__ indptr,
                                                     int* __restrict__ cursor,
                                                     const int* __restrict__ bsum, int N) {
    int i = blockIdx.x * 1024 + (int)threadIdx.x;
    if (i == 0) indptr[0] = 0;
    if (i < N) {
        int incl = indptr[i + 1] + bsum[blockIdx.x];
        indptr[i + 1] = incl;
        cursor[i] = incl - counts[i];
    }
}

// scatter src+dst node ids into CSR slots (order within a segment arbitrary)
__global__ void fill_kernel(const int* __restrict__ src, const int* __restrict__ dst,
                            int* __restrict__ cursor, int* __restrict__ csr_src,
                            int* __restrict__ csr_dst, int E) {
    int i = blockIdx.x * blockDim.x + threadIdx.x;
    if (i < E) {
        int d = dst[i];
        int pos = atomicAdd(&cursor[d], 1);
        csr_src[pos] = src[i];
        csr_dst[pos] = d;
    }
}

// ---------------------------------------------------------------------------
// Pack W1 [1024,256] fp32 into bf16 MFMA-B fragment order.
__global__ void pack_w1(const float* __restrict__ W, ushort* __restrict__ Bp) {
    int o = blockIdx.x * blockDim.x + threadIdx.x;   // 0 .. 262143
    int j = o & 7;
    int lane = (o >> 3) & 63;
    int kchunk = (o >> 9) & 31;
    int ntile = o >> 14;
    int k = kchunk * 32 + (lane >> 4) * 8 + j;
    int n = ntile * 16 + (lane & 15);
    Bp[o] = f2bf(W[k * 256 + n]);
}

// ---------------------------------------------------------------------------
// bf16 MFMA GEMM, layer 1: C[M,256] = A[M,1024] @ W1.
__global__ __launch_bounds__(256) void gemm1_mfma(const float* __restrict__ A,
                                                  const ushort* __restrict__ Bp,
                                                  float* __restrict__ C, int M) {
    __shared__ __align__(16) ushort Atile[128 * 32];   // 8 KB
    const int K = 1024, N = 256;
    int tid = threadIdx.x;
    int lane = tid & 63;
    int w = tid >> 6;
    int wm = w >> 1, wn = w & 1;
    int m0 = blockIdx.x * 128;
    int n0 = blockIdx.y * 128;

    const float* srow[4];
    int soff[4];
    #pragma unroll
    for (int l = 0; l < 4; ++l) {
        int slot = l * 256 + tid;
        int m = slot >> 3, hc = slot & 7;
        int c = hc >> 1;
        int row = m0 + m; if (row >= M) row = M - 1;
        srow[l] = A + (size_t)row * K + hc * 4;
        soff[l] = (m * 4 + (c ^ ((m >> 1) & 3))) * 8 + (hc & 1) * 4;
    }
    int afrag_off[4];
    #pragma unroll
    for (int mt = 0; mt < 4; ++mt) {
        int r = wm * 64 + mt * 16 + (lane & 15);
        int cq = lane >> 4;
        afrag_off[mt] = (r * 4 + (cq ^ ((r >> 1) & 3))) * 8;
    }
    const ushort* bbase[4];
    #pragma unroll
    for (int nt = 0; nt < 4; ++nt) {
        int ntile = blockIdx.y * 8 + wn * 4 + nt;
        bbase[nt] = Bp + ((size_t)(ntile * 32) * 64 + lane) * 8;
    }

    f32x4 acc[4][4] = {};

    for (int k0 = 0; k0 < K; k0 += 32) {
        #pragma unroll
        for (int l = 0; l < 4; ++l) {
            float4 v = *(const float4*)(srow[l] + k0);
            ushort4 b;
            b.x = f2bf(v.x); b.y = f2bf(v.y); b.z = f2bf(v.z); b.w = f2bf(v.w);
            *(ushort4*)&Atile[soff[l]] = b;
        }
        int kc = k0 >> 5;
        bf16x8 bfr[4];
        #pragma unroll
        for (int nt = 0; nt < 4; ++nt)
            bfr[nt] = *(const bf16x8*)(bbase[nt] + (size_t)kc * 64 * 8);
        __syncthreads();
        bf16x8 afr[4];
        #pragma unroll
        for (int mt = 0; mt < 4; ++mt)
            afr[mt] = *(const bf16x8*)&Atile[afrag_off[mt]];
        #pragma unroll
        for (int mt = 0; mt < 4; ++mt)
            #pragma unroll
            for (int nt = 0; nt < 4; ++nt)
                acc[mt][nt] = __builtin_amdgcn_mfma_f32_16x16x32_bf16(afr[mt], bfr[nt], acc[mt][nt], 0, 0, 0);
        __syncthreads();
    }
    #pragma unroll
    for (int mt = 0; mt < 4; ++mt) {
        #pragma unroll
        for (int nt = 0; nt < 4; ++nt) {
            int col = n0 + wn * 64 + nt * 16 + (lane & 15);
            #pragma unroll
            for (int r = 0; r < 4; ++r) {
                int row = m0 + wm * 64 + mt * 16 + (lane >> 4) * 4 + r;
                if (row < M) C[(size_t)row * N + col] = acc[mt][nt][r];
            }
        }
    }
}

// ---------------------------------------------------------------------------
// fp32 tiled GEMM (layer 2): C[M,N] = A[M,K] @ B[K,N].
__global__ __launch_bounds__(256) void gemm_tiled(const float* __restrict__ A,
                                                  const float* __restrict__ B,
                                                  float* __restrict__ C,
                                                  int M, int N, int K) {
    __shared__ __align__(16) float As[32][64];
    __shared__ __align__(16) float Bs[32][64];
    int tid = threadIdx.x;
    int tx = tid & 15, ty = tid >> 4;
    int m0 = blockIdx.x * 64, n0 = blockIdx.y * 64;
    float acc[4][4] = {};

    for (int k0 = 0; k0 < K; k0 += 32) {
        #pragma unroll
        for (int l = 0; l < 2; ++l) {
            int lin = tid + l * 256;
            int ar = lin >> 3;
            int ac = (lin & 7) << 2;
            float4 f = make_float4(0.f, 0.f, 0.f, 0.f);
            if (m0 + ar < M)
                f = *(const float4*)&A[(size_t)(m0 + ar) * K + k0 + ac];
            As[ac + 0][ar] = f.x; As[ac + 1][ar] = f.y;
            As[ac + 2][ar] = f.z; As[ac + 3][ar] = f.w;
        }
        #pragma unroll
        for (int l = 0; l < 2; ++l) {
            int lin = tid + l * 256;
            int br = lin >> 4;
            int bc = (lin & 15) << 2;
            *(float4*)&Bs[br][bc] = *(const float4*)&B[(size_t)(k0 + br) * N + n0 + bc];
        }
        __syncthreads();
        #pragma unroll
        for (int kk = 0; kk < 32; ++kk) {
            float4 a = *(const float4*)&As[kk][ty * 4];
            float4 b = *(const float4*)&Bs[kk][tx * 4];
            float av[4] = {a.x, a.y, a.z, a.w};
            float bv[4] = {b.x, b.y, b.z, b.w};
            #pragma unroll
            for (int i = 0; i < 4; ++i)
                #pragma unroll
                for (int j = 0; j < 4; ++j)
                    acc[i][j] += av[i] * bv[j];
        }
        __syncthreads();
    }
    #pragma unroll
    for (int i = 0; i < 4; ++i) {
        int m = m0 + ty * 4 + i;
        if (m < M) {
            float4 o = make_float4(acc[i][0], acc[i][1], acc[i][2], acc[i][3]);
            *(float4*)&C[(size_t)m * N + n0 + tx * 4] = o;
        }
    }
}

// ---------------------------------------------------------------------------
__device__ __forceinline__ float wave_reduce_sum(float v) {
    #pragma unroll
    for (int off = 32; off > 0; off >>= 1) v += __shfl_xor(v, off, 64);
    return v;
}

// al_s[n,h] = <h[n,h,:], asrc[h,:]>, al_d likewise. One wave per node; 4 nodes/block.
__global__ __launch_bounds__(256) void att_kernel(const float* __restrict__ h,
                                                  const float* __restrict__ asrc,
                                                  const float* __restrict__ adst,
                                                  float* __restrict__ al_s,
                                                  float* __restrict__ al_d,
                                                  int N, int H) {
    int lane = threadIdx.x & 63;
    int n = blockIdx.x * 4 + (threadIdx.x >> 6);
    if (n >= N) return;
    for (int hh = 0; hh < H; ++hh) {
        float hv = h[(size_t)n * H * 64 + hh * 64 + lane];
        float s = wave_reduce_sum(hv * asrc[hh * 64 + lane]);
        float d = wave_reduce_sum(hv * adst[hh * 64 + lane]);
        if (lane == 0) {
            al_s[n * H + hh] = s;
            al_d[n * H + hh] = d;
        }
    }
}

// Per-CSR-position softmax weights (no max subtraction: |logit| < ~5 here).
__global__ void edgew4_kernel(const float* __restrict__ als, const float* __restrict__ ald,
                              const int* __restrict__ csr_src, const int* __restrict__ csr_dst,
                              float* __restrict__ w, int E) {
    int p = blockIdx.x * blockDim.x + threadIdx.x;
    if (p >= E) return;
    int s = csr_src[p], d = csr_dst[p];
    float4 a = *(const float4*)&als[s * 4];
    float4 b = *(const float4*)&ald[d * 4];
    float4 o;
    float e;
    e = a.x + b.x; e = (e > 0.f) ? e : NEG_SLOPE * e; o.x = __expf(e);
    e = a.y + b.y; e = (e > 0.f) ? e : NEG_SLOPE * e; o.y = __expf(e);
    e = a.z + b.z; e = (e > 0.f) ? e : NEG_SLOPE * e; o.z = __expf(e);
    e = a.w + b.w; e = (e > 0.f) ? e : NEG_SLOPE * e; o.w = __expf(e);
    *(float4*)&w[p * 4] = o;
}

__global__ void edgew1_kernel(const float* __restrict__ als, const float* __restrict__ ald,
                              const int* __restrict__ csr_src, const int* __restrict__ csr_dst,
                              float* __restrict__ w, int E) {
    int p = blockIdx.x * blockDim.x + threadIdx.x;
    if (p >= E) return;
    float e = als[csr_src[p]] + ald[csr_dst[p]];
    e = (e > 0.f) ? e : NEG_SLOPE * e;
    w[p] = __expf(e);
}

// agg1: one node/block, 16 waves = 4 heads x 4 edge-slices, LDS combine.
__global__ __launch_bounds__(1024) void agg1_kernel(const float* __restrict__ h,
                                                    const float* __restrict__ w,
                                                    const int* __restrict__ indptr,
                                                    const int* __restrict__ csr_src,
                                                    const float* __restrict__ bias,
                                                    float* __restrict__ out, int N) {
    __shared__ float lds_acc[16][64];
    __shared__ float lds_den[16];
    int n = blockIdx.x;
    int lane = threadIdx.x & 63;
    int wv = threadIdx.x >> 6;         // 0..15
    int head = wv & 3, slice = wv >> 2;
    int beg = indptr[n], end = indptr[n + 1];
    float den = 0.f, acc = 0.f;
    for (int p = beg + slice; p < end; p += 4) {
        int s = csr_src[p];
        float wt = w[p * 4 + head];
        den += wt;
        acc = fmaf(wt, h[(size_t)s * 256 + head * 64 + lane], acc);
    }
    lds_acc[wv][lane] = acc;
    if (lane == 0) lds_den[wv] = den;
    __syncthreads();
    if (wv < 4) {
        int hd = wv;
        float a = lds_acc[hd][lane] + lds_acc[4 + hd][lane] +
                  lds_acc[8 + hd][lane] + lds_acc[12 + hd][lane];
        float d = lds_den[hd] + lds_den[4 + hd] + lds_den[8 + hd] + lds_den[12 + hd];
        float o = a / d + bias[hd * 64 + lane];
        o = (o > 0.f) ? o : (__expf(o) - 1.0f);
        out[(size_t)n * 256 + hd * 64 + lane] = o;
    }
}

// agg2: one node/block, 4 waves = 4 edge-slices (H=1), LDS combine.
__global__ __launch_bounds__(256) void agg2_kernel(const float* __restrict__ h,
                                                   const float* __restrict__ w,
                                                   const int* __restrict__ indptr,
                                                   const int* __restrict__ csr_src,
                                                   const float* __restrict__ bias,
                                                   float* __restrict__ out, int N) {
    __shared__ float lds_acc[4][64];
    __shared__ float lds_den[4];
    int n = blockIdx.x;
    int lane = threadIdx.x & 63;
    int wv = threadIdx.x >> 6;         // slice 0..3
    int beg = indptr[n], end = indptr[n + 1];
    float den = 0.f, acc = 0.f;
    for (int p = beg + wv; p < end; p += 4) {
        int s = csr_src[p];
        float wt = w[p];
        den += wt;
        acc = fmaf(wt, h[(size_t)s * 64 + lane], acc);
    }
    lds_acc[wv][lane] = acc;
    if (lane == 0) lds_den[wv] = den;
    __syncthreads();
    if (wv == 0) {
        float a = lds_acc[0][lane] + lds_acc[1][lane] + lds_acc[2][lane] + lds_acc[3][lane];
        float d = lds_den[0] + lds_den[1] + lds_den[2] + lds_den[3];
        float o = a / d + bias[lane];
        o = (o > 0.f) ? o : (__expf(o) - 1.0f);
        out[(size_t)n * 64 + lane] = o;
    }
}

// atomic mean-pool accumulation
__global__ void pool_kernel(const float* __restrict__ hfin, const int* __restrict__ batch,
                            float* __restrict__ pooled, float* __restrict__ gcnt, int N) {
    int gid = blockIdx.x * blockDim.x + threadIdx.x;
    int n = gid >> 6, c = gid & 63;
    if (n >= N) return;
    int g = batch[n];
    atomicAdd(&pooled[g * 64 + c], hfin[(size_t)n * 64 + c]);
    if (c == 0) atomicAdd(&gcnt[g], 1.0f);
}

// out[g,j] = (pooled[g,:]/cnt[g]) @ fc_w[:,j] + fc_b[j]
__global__ void final_kernel(const float* __restrict__ pooled, const float* __restrict__ gcnt,
                             const float* __restrict__ fc_w, const float* __restrict__ fc_b,
                             float* __restrict__ out) {
    int tid = threadIdx.x;
    if (tid >= NGRAPHS * 2) return;
    int g = tid >> 1, j = tid & 1;
    float cnt = fmaxf(gcnt[g], 1.0f);
    float s = 0.f;
    for (int c = 0; c < 64; ++c) s += pooled[g * 64 + c] * fc_w[c * 2 + j];
    out[g * 2 + j] = s / cnt + fc_b[j];
}

// ---------------------------------------------------------------------------
extern "C" void kernel_launch(void* const* d_in, const int* in_sizes, int n_in,
                              void* d_out, int out_size, void* d_ws, size_t ws_size,
                              hipStream_t stream) {
    const float* x      = (const float*)d_in[0];
    const int*   ei     = (const int*)d_in[1];
    const int*   batch  = (const int*)d_in[2];
    const float* W1     = (const float*)d_in[3];
    const float* asrc1  = (const float*)d_in[4];
    const float* adst1  = (const float*)d_in[5];
    const float* b1     = (const float*)d_in[6];
    const float* W2     = (const float*)d_in[7];
    const float* asrc2  = (const float*)d_in[8];
    const float* adst2  = (const float*)d_in[9];
    const float* b2     = (const float*)d_in[10];
    const float* fc_w   = (const float*)d_in[11];
    const float* fc_b   = (const float*)d_in[12];
    float* out          = (float*)d_out;

    const int N = in_sizes[2];          // 50000
    const int E = in_sizes[1] / 2;      // 850000
    const int* src = ei;
    const int* dst = ei + E;

    float* ws = (float*)d_ws;
    int*    counts  = (int*)(ws + WS_COUNTS);
    float*  pooled  = ws + WS_POOLED;
    float*  gcnt    = ws + WS_GCNT;
    int*    indptr  = (int*)(ws + WS_INDPTR);
    int*    cursor  = (int*)(ws + WS_CURSOR);
    int*    csr_src = (int*)(ws + WS_CSRSRC);
    int*    csr_dst = (int*)(ws + WS_CSRDST);
    float*  al_s1   = ws + WS_ALS1;
    float*  al_d1   = ws + WS_ALD1;
    float*  al_s2   = ws + WS_ALS2;
    float*  al_d2   = ws + WS_ALD2;
    float*  h1      = ws + WS_H1;
    float*  x2      = ws + WS_X2;
    ushort* bp      = (ushort*)(ws + WS_BP);
    float*  w1e     = ws + WS_W1E;
    float*  w2e     = ws + WS_W1E;    // alias (w1e dead before edgew1_kernel runs)
    int*    bsum    = (int*)(ws + WS_BSUM);
    float*  h2      = ws + WS_H2;     // aliases h1 (h1 dead after agg1)
    float*  hfin    = ws + WS_HFIN;   // aliases h1 tail

    const int nb = (N + 1023) / 1024;   // scan blocks (<=64)

    // 1. zero counts + pooled + gcnt; pack W1 to bf16 fragment order
    zero_kernel<<<(WS_ZEROLEN + 255) / 256, 256, 0, stream>>>(ws, WS_ZEROLEN);
    pack_w1<<<(INDIM * F1) / 256, 256, 0, stream>>>(W1, bp);
    // 2. CSR build (by dst): hist -> 3-kernel scan -> fill
    hist_kernel<<<(E + 255) / 256, 256, 0, stream>>>(dst, counts, E);
    scan1_kernel<<<nb, 1024, 0, stream>>>(counts, indptr, bsum, N);
    scan2_kernel<<<1, 64, 0, stream>>>(bsum, nb);
    scan3_kernel<<<nb, 1024, 0, stream>>>(counts, indptr, cursor, bsum, N);
    fill_kernel<<<(E + 255) / 256, 256, 0, stream>>>(src, dst, cursor, csr_src, csr_dst, E);
    // 3. layer 1: h1 = x @ W1  via bf16 MFMA  [50000,1024]x[1024,256]
    gemm1_mfma<<<dim3((N + 127) / 128, F1 / 128), 256, 0, stream>>>(x, bp, h1, N);
    // 4. attention logits + per-edge softmax weights
    att_kernel<<<(N + 3) / 4, 256, 0, stream>>>(h1, asrc1, adst1, al_s1, al_d1, N, HEADS1);
    edgew4_kernel<<<(E + 255) / 256, 256, 0, stream>>>(al_s1, al_d1, csr_src, csr_dst, w1e, E);
    // 5. aggregate + bias + ELU -> x2
    agg1_kernel<<<N, 1024, 0, stream>>>(h1, w1e, indptr, csr_src, b1, x2, N);
    // 6. layer 2: h2 = x2 @ W2  [50000,256]x[256,64]  (fp32, small)
    gemm_tiled<<<dim3((N + 63) / 64, 1), 256, 0, stream>>>(x2, W2, h2, N, HIDC, F1);
    // 7. attention logits + weights layer 2
    att_kernel<<<(N + 3) / 4, 256, 0, stream>>>(h2, asrc2, adst2, al_s2, al_d2, N, 1);
    edgew1_kernel<<<(E + 255) / 256, 256, 0, stream>>>(al_s2, al_d2, csr_src, csr_dst, w2e, E);
    // 8. aggregate + bias + ELU -> hfin
    agg2_kernel<<<N, 256, 0, stream>>>(h2, w2e, indptr, csr_src, b2, hfin, N);
    // 9. mean pool + FC
    pool_kernel<<<((N * 64) + 255) / 256, 256, 0, stream>>>(hfin, batch, pooled, gcnt, N);
    final_kernel<<<1, 128, 0, stream>>>(pooled, gcnt, fc_w, fc_b, out);
}

// Round 4
// 973.062 us; speedup vs baseline: 1.8023x; 1.3409x over previous
//
#include <hip/hip_runtime.h>
#include <hip/hip_bf16.h>

// Problem constants (fixed by the reference setup)
#define NNODES   50000
#define NGRAPHS  64
#define INDIM    1024
#define HIDC     64      // channels per head
#define HEADS1   4
#define F1       (HEADS1*HIDC)   // 256
#define NEG_SLOPE 0.2f

// ---------------------------------------------------------------------------
// Workspace layout (4-byte words). All vector-accessed buffers 16B-aligned.
#define WS_COUNTS   0                    // int[50000]
#define WS_POOLED   50000                // float[4096]
#define WS_GCNT     54096                // float[64]
#define WS_ZEROLEN  54160                // words to zero
#define WS_INDPTR   54208                // int[50001]
#define WS_CURSOR   104256               // int[50000]
#define WS_CSRSRC   154304               // int[850000]
#define WS_CSRDST   1004304              // int[850000]
#define WS_BSUM     1854304              // int[64]
#define WS_ALS1     1854368              // float[200000]
#define WS_ALD1     2054368              // float[200000]
#define WS_ALS2     2254368              // float[50000]
#define WS_ALD2     2304368              // float[50000]
#define WS_BP       2354368              // ushort[262144] (packed bf16 W1)
#define WS_BP2      2485440              // ushort[16384]  (packed bf16 W2)
#define WS_H1B      2493632              // ushort[12,800,000] bf16 h1
#define WS_X2B      8893632              // ushort[12,800,000] bf16 x2
#define WS_H2B      15293632             // ushort[3,200,000]  bf16 h2
#define WS_W1E      16893632             // float[3,400,000] (w2e aliases; w1e dead by then)
#define WS_HFIN     20293632             // float[3,200,000]

typedef __attribute__((ext_vector_type(8))) short bf16x8;
typedef __attribute__((ext_vector_type(4))) float f32x4;

__device__ __forceinline__ ushort f2bf(float f) {
    union { float f; uint u; } v; v.f = f;
    uint r = v.u + 0x7fff + ((v.u >> 16) & 1);   // round-to-nearest-even
    return (ushort)(r >> 16);
}
__device__ __forceinline__ float bf2f(ushort u) {
    union { uint u; float f; } v; v.u = (uint)u << 16; return v.f;
}

// ---------------------------------------------------------------------------
__global__ void zero_kernel(float* p, int n) {
    int i = blockIdx.x * blockDim.x + threadIdx.x;
    if (i < n) p[i] = 0.0f;
}

__global__ void hist_kernel(const int* __restrict__ dst, int* __restrict__ counts, int E) {
    int i = blockIdx.x * blockDim.x + threadIdx.x;
    if (i < E) atomicAdd(&counts[dst[i]], 1);
}

// --- 3-kernel multi-block scan -------------------------------------------
__global__ __launch_bounds__(1024) void scan1_kernel(const int* __restrict__ counts,
                                                     int* __restrict__ indptr,
                                                     int* __restrict__ bsum, int N) {
    __shared__ int sm[1024];
    int b = blockIdx.x;
    int i = b * 1024 + (int)threadIdx.x;
    int v = (i < N) ? counts[i] : 0;
    sm[threadIdx.x] = v;
    __syncthreads();
    for (int off = 1; off < 1024; off <<= 1) {
        int t = (threadIdx.x >= (unsigned)off) ? sm[threadIdx.x - off] : 0;
        __syncthreads();
        sm[threadIdx.x] += t;
        __syncthreads();
    }
    if (i < N) indptr[i + 1] = sm[threadIdx.x];
    if (threadIdx.x == 1023) bsum[b] = sm[1023];
}

__global__ void scan2_kernel(int* __restrict__ bsum, int nb) {
    int lane = threadIdx.x;
    int v = (lane < nb) ? bsum[lane] : 0;
    int orig = v;
    #pragma unroll
    for (int off = 1; off < 64; off <<= 1) {
        int t = __shfl_up(v, off, 64);
        if (lane >= off) v += t;
    }
    if (lane < nb) bsum[lane] = v - orig;   // exclusive
}

__global__ __launch_bounds__(1024) void scan3_kernel(const int* __restrict__ counts,
                                                     int* __restrict__ indptr,
                                                     int* __restrict__ cursor,
                                                     const int* __restrict__ bsum, int N) {
    int i = blockIdx.x * 1024 + (int)threadIdx.x;
    if (i == 0) indptr[0] = 0;
    if (i < N) {
        int incl = indptr[i + 1] + bsum[blockIdx.x];
        indptr[i + 1] = incl;
        cursor[i] = incl - counts[i];
    }
}

__global__ void fill_kernel(const int* __restrict__ src, const int* __restrict__ dst,
                            int* __restrict__ cursor, int* __restrict__ csr_src,
                            int* __restrict__ csr_dst, int E) {
    int i = blockIdx.x * blockDim.x + threadIdx.x;
    if (i < E) {
        int d = dst[i];
        int pos = atomicAdd(&cursor[d], 1);
        csr_src[pos] = src[i];
        csr_dst[pos] = d;
    }
}

// ---------------------------------------------------------------------------
// Pack W1 [1024,256] fp32 into bf16 MFMA-B fragment order.
__global__ void pack_w1(const float* __restrict__ W, ushort* __restrict__ Bp) {
    int o = blockIdx.x * blockDim.x + threadIdx.x;   // 0 .. 262143
    int j = o & 7;
    int lane = (o >> 3) & 63;
    int kchunk = (o >> 9) & 31;
    int ntile = o >> 14;
    int k = kchunk * 32 + (lane >> 4) * 8 + j;
    int n = ntile * 16 + (lane & 15);
    Bp[o] = f2bf(W[k * 256 + n]);
}

// Pack W2 [256,64] fp32 into bf16 MFMA-B fragment order (4 ntiles, 8 kchunks).
__global__ void pack_w2(const float* __restrict__ W, ushort* __restrict__ Bp) {
    int o = blockIdx.x * blockDim.x + threadIdx.x;   // 0 .. 16383
    int j = o & 7;
    int lane = (o >> 3) & 63;
    int kchunk = (o >> 9) & 7;
    int ntile = o >> 12;
    int k = kchunk * 32 + (lane >> 4) * 8 + j;
    int n = ntile * 16 + (lane & 15);
    Bp[o] = f2bf(W[k * 64 + n]);
}

// ---------------------------------------------------------------------------
// bf16 MFMA GEMM, layer 1: h1b[M,256](bf16) = A[M,1024](fp32) @ W1.
__global__ __launch_bounds__(256) void gemm1_mfma(const float* __restrict__ A,
                                                  const ushort* __restrict__ Bp,
                                                  ushort* __restrict__ C, int M) {
    __shared__ __align__(16) ushort Atile[128 * 32];   // 8 KB
    const int K = 1024, N = 256;
    int tid = threadIdx.x;
    int lane = tid & 63;
    int w = tid >> 6;
    int wm = w >> 1, wn = w & 1;
    int m0 = blockIdx.x * 128;
    int n0 = blockIdx.y * 128;

    const float* srow[4];
    int soff[4];
    #pragma unroll
    for (int l = 0; l < 4; ++l) {
        int slot = l * 256 + tid;
        int m = slot >> 3, hc = slot & 7;
        int c = hc >> 1;
        int row = m0 + m; if (row >= M) row = M - 1;
        srow[l] = A + (size_t)row * K + hc * 4;
        soff[l] = (m * 4 + (c ^ ((m >> 1) & 3))) * 8 + (hc & 1) * 4;
    }
    int afrag_off[4];
    #pragma unroll
    for (int mt = 0; mt < 4; ++mt) {
        int r = wm * 64 + mt * 16 + (lane & 15);
        int cq = lane >> 4;
        afrag_off[mt] = (r * 4 + (cq ^ ((r >> 1) & 3))) * 8;
    }
    const ushort* bbase[4];
    #pragma unroll
    for (int nt = 0; nt < 4; ++nt) {
        int ntile = blockIdx.y * 8 + wn * 4 + nt;
        bbase[nt] = Bp + ((size_t)(ntile * 32) * 64 + lane) * 8;
    }

    f32x4 acc[4][4] = {};

    for (int k0 = 0; k0 < K; k0 += 32) {
        #pragma unroll
        for (int l = 0; l < 4; ++l) {
            float4 v = *(const float4*)(srow[l] + k0);
            ushort4 b;
            b.x = f2bf(v.x); b.y = f2bf(v.y); b.z = f2bf(v.z); b.w = f2bf(v.w);
            *(ushort4*)&Atile[soff[l]] = b;
        }
        int kc = k0 >> 5;
        bf16x8 bfr[4];
        #pragma unroll
        for (int nt = 0; nt < 4; ++nt)
            bfr[nt] = *(const bf16x8*)(bbase[nt] + (size_t)kc * 64 * 8);
        __syncthreads();
        bf16x8 afr[4];
        #pragma unroll
        for (int mt = 0; mt < 4; ++mt)
            afr[mt] = *(const bf16x8*)&Atile[afrag_off[mt]];
        #pragma unroll
        for (int mt = 0; mt < 4; ++mt)
            #pragma unroll
            for (int nt = 0; nt < 4; ++nt)
                acc[mt][nt] = __builtin_amdgcn_mfma_f32_16x16x32_bf16(afr[mt], bfr[nt], acc[mt][nt], 0, 0, 0);
        __syncthreads();
    }
    #pragma unroll
    for (int mt = 0; mt < 4; ++mt) {
        #pragma unroll
        for (int nt = 0; nt < 4; ++nt) {
            int col = n0 + wn * 64 + nt * 16 + (lane & 15);
            #pragma unroll
            for (int r = 0; r < 4; ++r) {
                int row = m0 + wm * 64 + mt * 16 + (lane >> 4) * 4 + r;
                if (row < M) C[(size_t)row * N + col] = f2bf(acc[mt][nt][r]);
            }
        }
    }
}

// ---------------------------------------------------------------------------
// bf16 MFMA GEMM, layer 2: h2b[M,64](bf16) = x2b[M,256](bf16) @ W2.
// No LDS: A-fragments loaded straight from global (x2b is L2/LLC resident).
__global__ __launch_bounds__(256) void gemm2_mfma(const ushort* __restrict__ Ab,
                                                  const ushort* __restrict__ Bp,
                                                  ushort* __restrict__ C, int M) {
    int tid = threadIdx.x;
    int lane = tid & 63;
    int w = tid >> 6;
    int m0 = blockIdx.x * 128 + w * 32;

    f32x4 acc[2][4] = {};
    #pragma unroll 2
    for (int kc = 0; kc < 8; ++kc) {
        bf16x8 afr[2];
        #pragma unroll
        for (int mt = 0; mt < 2; ++mt) {
            int r = m0 + mt * 16 + (lane & 15);
            if (r >= M) r = M - 1;
            afr[mt] = *(const bf16x8*)&Ab[(size_t)r * 256 + kc * 32 + (lane >> 4) * 8];
        }
        #pragma unroll
        for (int nt = 0; nt < 4; ++nt) {
            bf16x8 bfr = *(const bf16x8*)&Bp[((nt * 8 + kc) * 64 + lane) * 8];
            acc[0][nt] = __builtin_amdgcn_mfma_f32_16x16x32_bf16(afr[0], bfr, acc[0][nt], 0, 0, 0);
            acc[1][nt] = __builtin_amdgcn_mfma_f32_16x16x32_bf16(afr[1], bfr, acc[1][nt], 0, 0, 0);
        }
    }
    #pragma unroll
    for (int mt = 0; mt < 2; ++mt) {
        #pragma unroll
        for (int nt = 0; nt < 4; ++nt) {
            int col = nt * 16 + (lane & 15);
            #pragma unroll
            for (int r = 0; r < 4; ++r) {
                int row = m0 + mt * 16 + (lane >> 4) * 4 + r;
                if (row < M) C[(size_t)row * 64 + col] = f2bf(acc[mt][nt][r]);
            }
        }
    }
}

// ---------------------------------------------------------------------------
__device__ __forceinline__ float wave_reduce_sum(float v) {
    #pragma unroll
    for (int off = 32; off > 0; off >>= 1) v += __shfl_xor(v, off, 64);
    return v;
}

// logits from bf16 features. One wave per node; 4 nodes/block.
__global__ __launch_bounds__(256) void att_kernel(const ushort* __restrict__ h,
                                                  const float* __restrict__ asrc,
                                                  const float* __restrict__ adst,
                                                  float* __restrict__ al_s,
                                                  float* __restrict__ al_d,
                                                  int N, int H) {
    int lane = threadIdx.x & 63;
    int n = blockIdx.x * 4 + (threadIdx.x >> 6);
    if (n >= N) return;
    for (int hh = 0; hh < H; ++hh) {
        float hv = bf2f(h[(size_t)n * H * 64 + hh * 64 + lane]);
        float s = wave_reduce_sum(hv * asrc[hh * 64 + lane]);
        float d = wave_reduce_sum(hv * adst[hh * 64 + lane]);
        if (lane == 0) {
            al_s[n * H + hh] = s;
            al_d[n * H + hh] = d;
        }
    }
}

// Per-CSR-position softmax weights (no max subtraction: |logit| small here).
__global__ void edgew4_kernel(const float* __restrict__ als, const float* __restrict__ ald,
                              const int* __restrict__ csr_src, const int* __restrict__ csr_dst,
                              float* __restrict__ w, int E) {
    int p = blockIdx.x * blockDim.x + threadIdx.x;
    if (p >= E) return;
    int s = csr_src[p], d = csr_dst[p];
    float4 a = *(const float4*)&als[s * 4];
    float4 b = *(const float4*)&ald[d * 4];
    float4 o;
    float e;
    e = a.x + b.x; e = (e > 0.f) ? e : NEG_SLOPE * e; o.x = __expf(e);
    e = a.y + b.y; e = (e > 0.f) ? e : NEG_SLOPE * e; o.y = __expf(e);
    e = a.z + b.z; e = (e > 0.f) ? e : NEG_SLOPE * e; o.z = __expf(e);
    e = a.w + b.w; e = (e > 0.f) ? e : NEG_SLOPE * e; o.w = __expf(e);
    *(float4*)&w[p * 4] = o;
}

__global__ void edgew1_kernel(const float* __restrict__ als, const float* __restrict__ ald,
                              const int* __restrict__ csr_src, const int* __restrict__ csr_dst,
                              float* __restrict__ w, int E) {
    int p = blockIdx.x * blockDim.x + threadIdx.x;
    if (p >= E) return;
    float e = als[csr_src[p]] + ald[csr_dst[p]];
    e = (e > 0.f) ? e : NEG_SLOPE * e;
    w[p] = __expf(e);
}

// agg1: one node/block, 4 waves = 4 edge slices. Each wave fetches the FULL
// 512-B bf16 row (all 4 heads) in one ushort4/lane instruction; 2x unrolled.
// lane covers cols lane*4..lane*4+3; head = lane>>4.
__global__ __launch_bounds__(256) void agg1_kernel(const ushort* __restrict__ h,
                                                   const float* __restrict__ w,
                                                   const int* __restrict__ indptr,
                                                   const int* __restrict__ csr_src,
                                                   const float* __restrict__ bias,
                                                   ushort* __restrict__ out, int N) {
    __shared__ float4 lacc[4][64];
    __shared__ float  lden[4][64];
    int n = blockIdx.x;
    int lane = threadIdx.x & 63;
    int wv = threadIdx.x >> 6;
    int hd = lane >> 4;
    int beg = indptr[n], end = indptr[n + 1];
    float4 acc = make_float4(0.f, 0.f, 0.f, 0.f);
    float den = 0.f;
    int p = beg + wv;
    for (; p + 4 < end; p += 8) {
        int s0 = csr_src[p], s1 = csr_src[p + 4];
        float w0 = w[p * 4 + hd], w1 = w[(p + 4) * 4 + hd];
        ushort4 a0 = *(const ushort4*)&h[(size_t)s0 * 256 + lane * 4];
        ushort4 a1 = *(const ushort4*)&h[(size_t)s1 * 256 + lane * 4];
        acc.x = fmaf(w0, bf2f(a0.x), fmaf(w1, bf2f(a1.x), acc.x));
        acc.y = fmaf(w0, bf2f(a0.y), fmaf(w1, bf2f(a1.y), acc.y));
        acc.z = fmaf(w0, bf2f(a0.z), fmaf(w1, bf2f(a1.z), acc.z));
        acc.w = fmaf(w0, bf2f(a0.w), fmaf(w1, bf2f(a1.w), acc.w));
        den += w0 + w1;
    }
    if (p < end) {
        int s0 = csr_src[p];
        float w0 = w[p * 4 + hd];
        ushort4 a0 = *(const ushort4*)&h[(size_t)s0 * 256 + lane * 4];
        acc.x = fmaf(w0, bf2f(a0.x), acc.x);
        acc.y = fmaf(w0, bf2f(a0.y), acc.y);
        acc.z = fmaf(w0, bf2f(a0.z), acc.z);
        acc.w = fmaf(w0, bf2f(a0.w), acc.w);
        den += w0;
    }
    lacc[wv][lane] = acc;
    lden[wv][lane] = den;
    __syncthreads();
    if (wv == 0) {
        float4 a = lacc[0][lane];
        float4 a1 = lacc[1][lane], a2 = lacc[2][lane], a3 = lacc[3][lane];
        a.x += a1.x + a2.x + a3.x;
        a.y += a1.y + a2.y + a3.y;
        a.z += a1.z + a2.z + a3.z;
        a.w += a1.w + a2.w + a3.w;
        float d = lden[0][lane] + lden[1][lane] + lden[2][lane] + lden[3][lane];
        float4 bv = *(const float4*)&bias[lane * 4];
        float inv = 1.0f / d;
        float o0 = a.x * inv + bv.x, o1 = a.y * inv + bv.y;
        float o2 = a.z * inv + bv.z, o3 = a.w * inv + bv.w;
        o0 = (o0 > 0.f) ? o0 : (__expf(o0) - 1.0f);
        o1 = (o1 > 0.f) ? o1 : (__expf(o1) - 1.0f);
        o2 = (o2 > 0.f) ? o2 : (__expf(o2) - 1.0f);
        o3 = (o3 > 0.f) ? o3 : (__expf(o3) - 1.0f);
        ushort4 ob; ob.x = f2bf(o0); ob.y = f2bf(o1); ob.z = f2bf(o2); ob.w = f2bf(o3);
        *(ushort4*)&out[(size_t)n * 256 + lane * 4] = ob;
    }
}

// agg2: one node/block, 4 waves = 8 half-wave slices. Each half-wave fetches a
// full 128-B bf16 row (ushort2/lane x 32 lanes). Output hfin fp32.
__global__ __launch_bounds__(256) void agg2_kernel(const ushort* __restrict__ h,
                                                   const float* __restrict__ w,
                                                   const int* __restrict__ indptr,
                                                   const int* __restrict__ csr_src,
                                                   const float* __restrict__ bias,
                                                   float* __restrict__ out, int N) {
    __shared__ float2 lacc[8][32];
    __shared__ float  lden[8][32];
    int n = blockIdx.x;
    int lane = threadIdx.x & 63;
    int wv = threadIdx.x >> 6;
    int sl = wv * 2 + (lane >> 5);    // slice 0..7
    int l32 = lane & 31;
    int beg = indptr[n], end = indptr[n + 1];
    float2 acc = make_float2(0.f, 0.f);
    float den = 0.f;
    for (int p = beg + sl; p < end; p += 8) {
        int s = csr_src[p];
        float wt = w[p];
        ushort2 hv = *(const ushort2*)&h[(size_t)s * 64 + l32 * 2];
        acc.x = fmaf(wt, bf2f(hv.x), acc.x);
        acc.y = fmaf(wt, bf2f(hv.y), acc.y);
        den += wt;
    }
    lacc[sl][l32] = acc;
    lden[sl][l32] = den;
    __syncthreads();
    if (threadIdx.x < 32) {
        int c = threadIdx.x;
        float2 a = make_float2(0.f, 0.f);
        float d = 0.f;
        #pragma unroll
        for (int s = 0; s < 8; ++s) {
            a.x += lacc[s][c].x; a.y += lacc[s][c].y;
            d += lden[s][c];
        }
        float inv = 1.0f / d;
        float o0 = a.x * inv + bias[c * 2];
        float o1 = a.y * inv + bias[c * 2 + 1];
        o0 = (o0 > 0.f) ? o0 : (__expf(o0) - 1.0f);
        o1 = (o1 > 0.f) ? o1 : (__expf(o1) - 1.0f);
        *(float2*)&out[(size_t)n * 64 + c * 2] = make_float2(o0, o1);
    }
}

// atomic mean-pool accumulation
__global__ void pool_kernel(const float* __restrict__ hfin, const int* __restrict__ batch,
                            float* __restrict__ pooled, float* __restrict__ gcnt, int N) {
    int gid = blockIdx.x * blockDim.x + threadIdx.x;
    int n = gid >> 6, c = gid & 63;
    if (n >= N) return;
    int g = batch[n];
    atomicAdd(&pooled[g * 64 + c], hfin[(size_t)n * 64 + c]);
    if (c == 0) atomicAdd(&gcnt[g], 1.0f);
}

__global__ void final_kernel(const float* __restrict__ pooled, const float* __restrict__ gcnt,
                             const float* __restrict__ fc_w, const float* __restrict__ fc_b,
                             float* __restrict__ out) {
    int tid = threadIdx.x;
    if (tid >= NGRAPHS * 2) return;
    int g = tid >> 1, j = tid & 1;
    float cnt = fmaxf(gcnt[g], 1.0f);
    float s = 0.f;
    for (int c = 0; c < 64; ++c) s += pooled[g * 64 + c] * fc_w[c * 2 + j];
    out[g * 2 + j] = s / cnt + fc_b[j];
}

// ---------------------------------------------------------------------------
extern "C" void kernel_launch(void* const* d_in, const int* in_sizes, int n_in,
                              void* d_out, int out_size, void* d_ws, size_t ws_size,
                              hipStream_t stream) {
    const float* x      = (const float*)d_in[0];
    const int*   ei     = (const int*)d_in[1];
    const int*   batch  = (const int*)d_in[2];
    const float* W1     = (const float*)d_in[3];
    const float* asrc1  = (const float*)d_in[4];
    const float* adst1  = (const float*)d_in[5];
    const float* b1     = (const float*)d_in[6];
    const float* W2     = (const float*)d_in[7];
    const float* asrc2  = (const float*)d_in[8];
    const float* adst2  = (const float*)d_in[9];
    const float* b2     = (const float*)d_in[10];
    const float* fc_w   = (const float*)d_in[11];
    const float* fc_b   = (const float*)d_in[12];
    float* out          = (float*)d_out;

    const int N = in_sizes[2];          // 50000
    const int E = in_sizes[1] / 2;      // 850000
    const int* src = ei;
    const int* dst = ei + E;

    float* ws = (float*)d_ws;
    int*    counts  = (int*)(ws + WS_COUNTS);
    float*  pooled  = ws + WS_POOLED;
    float*  gcnt    = ws + WS_GCNT;
    int*    indptr  = (int*)(ws + WS_INDPTR);
    int*    cursor  = (int*)(ws + WS_CURSOR);
    int*    csr_src = (int*)(ws + WS_CSRSRC);
    int*    csr_dst = (int*)(ws + WS_CSRDST);
    int*    bsum    = (int*)(ws + WS_BSUM);
    float*  al_s1   = ws + WS_ALS1;
    float*  al_d1   = ws + WS_ALD1;
    float*  al_s2   = ws + WS_ALS2;
    float*  al_d2   = ws + WS_ALD2;
    ushort* bp      = (ushort*)(ws + WS_BP);
    ushort* bp2     = (ushort*)(ws + WS_BP2);
    ushort* h1b     = (ushort*)(ws + WS_H1B);
    ushort* x2b     = (ushort*)(ws + WS_X2B);
    ushort* h2b     = (ushort*)(ws + WS_H2B);
    float*  w1e     = ws + WS_W1E;
    float*  w2e     = ws + WS_W1E;    // alias (w1e dead before edgew1_kernel)
    float*  hfin    = ws + WS_HFIN;

    const int nb = (N + 1023) / 1024;   // scan blocks (<=64)

    // 1. zero counts+pooled+gcnt; pack weights to bf16 fragment order
    zero_kernel<<<(WS_ZEROLEN + 255) / 256, 256, 0, stream>>>(ws, WS_ZEROLEN);
    pack_w1<<<(INDIM * F1) / 256, 256, 0, stream>>>(W1, bp);
    pack_w2<<<(F1 * HIDC) / 256, 256, 0, stream>>>(W2, bp2);
    // 2. CSR build (by dst)
    hist_kernel<<<(E + 255) / 256, 256, 0, stream>>>(dst, counts, E);
    scan1_kernel<<<nb, 1024, 0, stream>>>(counts, indptr, bsum, N);
    scan2_kernel<<<1, 64, 0, stream>>>(bsum, nb);
    scan3_kernel<<<nb, 1024, 0, stream>>>(counts, indptr, cursor, bsum, N);
    fill_kernel<<<(E + 255) / 256, 256, 0, stream>>>(src, dst, cursor, csr_src, csr_dst, E);
    // 3. layer 1 GEMM -> h1b (bf16)
    gemm1_mfma<<<dim3((N + 127) / 128, F1 / 128), 256, 0, stream>>>(x, bp, h1b, N);
    // 4. attention logits + per-edge softmax weights
    att_kernel<<<(N + 3) / 4, 256, 0, stream>>>(h1b, asrc1, adst1, al_s1, al_d1, N, HEADS1);
    edgew4_kernel<<<(E + 255) / 256, 256, 0, stream>>>(al_s1, al_d1, csr_src, csr_dst, w1e, E);
    // 5. aggregate + bias + ELU -> x2b (bf16)
    agg1_kernel<<<N, 256, 0, stream>>>(h1b, w1e, indptr, csr_src, b1, x2b, N);
    // 6. layer 2 GEMM -> h2b (bf16)
    gemm2_mfma<<<(N + 127) / 128, 256, 0, stream>>>(x2b, bp2, h2b, N);
    // 7. attention logits + weights layer 2
    att_kernel<<<(N + 3) / 4, 256, 0, stream>>>(h2b, asrc2, adst2, al_s2, al_d2, N, 1);
    edgew1_kernel<<<(E + 255) / 256, 256, 0, stream>>>(al_s2, al_d2, csr_src, csr_dst, w2e, E);
    // 8. aggregate + bias + ELU -> hfin (fp32)
    agg2_kernel<<<N, 256, 0, stream>>>(h2b, w2e, indptr, csr_src, b2, hfin, N);
    // 9. mean pool + FC
    pool_kernel<<<((N * 64) + 255) / 256, 256, 0, stream>>>(hfin, batch, pooled, gcnt, N);
    final_kernel<<<1, 128, 0, stream>>>(pooled, gcnt, fc_w, fc_b, out);
}

// Round 5
// 703.449 us; speedup vs baseline: 2.4930x; 1.3833x over previous
//
#include <hip/hip_runtime.h>
#include <hip/hip_bf16.h>

// Problem constants (fixed by the reference setup)
#define NNODES   50000
#define NGRAPHS  64
#define INDIM    1024
#define HIDC     64      // channels per head
#define HEADS1   4
#define F1       (HEADS1*HIDC)   // 256
#define NEG_SLOPE 0.2f

// ---------------------------------------------------------------------------
// Workspace layout (4-byte words). All vector-accessed buffers 16B-aligned.
#define WS_COUNTS   0                    // int[50000]
#define WS_POOLED   50000                // (unused, kept for layout stability)
#define WS_GCNT     54096                // (unused)
#define WS_ZEROLEN  50000                // words to zero (counts only)
#define WS_INDPTR   54208                // int[50001]
#define WS_CURSOR   104256               // int[50000]
#define WS_CSRSRC   154304               // int[850000]
#define WS_CSRDST   1004304              // int[850000]
#define WS_BSUM     1854304              // int[64]
#define WS_ALS1     1854368              // float[200000]
#define WS_ALD1     2054368              // float[200000]
#define WS_ALS2     2254368              // float[50000]
#define WS_ALD2     2304368              // float[50000]
#define WS_BP       2354368              // ushort[262144] (packed bf16 W1)
#define WS_BP2      2485440              // ushort[16384]  (packed bf16 W2)
#define WS_H1B      2493632              // ushort[12,800,000] bf16 h1
#define WS_X2B      8893632              // ushort[12,800,000] bf16 x2
#define WS_H2B      15293632             // ushort[3,200,000]  bf16 h2
#define WS_W1E      16893632             // float[3,400,000] (w2e aliases; w1e dead by then)
#define WS_HFIN     20293632             // float[3,200,000]

typedef __attribute__((ext_vector_type(8))) short bf16x8;
typedef __attribute__((ext_vector_type(4))) float f32x4;

__device__ __forceinline__ ushort f2bf(float f) {
    union { float f; uint u; } v; v.f = f;
    uint r = v.u + 0x7fff + ((v.u >> 16) & 1);   // round-to-nearest-even
    return (ushort)(r >> 16);
}
__device__ __forceinline__ float bf2f(ushort u) {
    union { uint u; float f; } v; v.u = (uint)u << 16; return v.f;
}

// ---------------------------------------------------------------------------
__global__ void zero_kernel(float* p, int n) {
    int i = blockIdx.x * blockDim.x + threadIdx.x;
    if (i < n) p[i] = 0.0f;
}

__global__ void hist_kernel(const int* __restrict__ dst, int* __restrict__ counts, int E) {
    int i = blockIdx.x * blockDim.x + threadIdx.x;
    if (i < E) atomicAdd(&counts[dst[i]], 1);
}

// --- 3-kernel multi-block scan -------------------------------------------
__global__ __launch_bounds__(1024) void scan1_kernel(const int* __restrict__ counts,
                                                     int* __restrict__ indptr,
                                                     int* __restrict__ bsum, int N) {
    __shared__ int sm[1024];
    int b = blockIdx.x;
    int i = b * 1024 + (int)threadIdx.x;
    int v = (i < N) ? counts[i] : 0;
    sm[threadIdx.x] = v;
    __syncthreads();
    for (int off = 1; off < 1024; off <<= 1) {
        int t = (threadIdx.x >= (unsigned)off) ? sm[threadIdx.x - off] : 0;
        __syncthreads();
        sm[threadIdx.x] += t;
        __syncthreads();
    }
    if (i < N) indptr[i + 1] = sm[threadIdx.x];
    if (threadIdx.x == 1023) bsum[b] = sm[1023];
}

__global__ void scan2_kernel(int* __restrict__ bsum, int nb) {
    int lane = threadIdx.x;
    int v = (lane < nb) ? bsum[lane] : 0;
    int orig = v;
    #pragma unroll
    for (int off = 1; off < 64; off <<= 1) {
        int t = __shfl_up(v, off, 64);
        if (lane >= off) v += t;
    }
    if (lane < nb) bsum[lane] = v - orig;   // exclusive
}

__global__ __launch_bounds__(1024) void scan3_kernel(const int* __restrict__ counts,
                                                     int* __restrict__ indptr,
                                                     int* __restrict__ cursor,
                                                     const int* __restrict__ bsum, int N) {
    int i = blockIdx.x * 1024 + (int)threadIdx.x;
    if (i == 0) indptr[0] = 0;
    if (i < N) {
        int incl = indptr[i + 1] + bsum[blockIdx.x];
        indptr[i + 1] = incl;
        cursor[i] = incl - counts[i];
    }
}

__global__ void fill_kernel(const int* __restrict__ src, const int* __restrict__ dst,
                            int* __restrict__ cursor, int* __restrict__ csr_src,
                            int* __restrict__ csr_dst, int E) {
    int i = blockIdx.x * blockDim.x + threadIdx.x;
    if (i < E) {
        int d = dst[i];
        int pos = atomicAdd(&cursor[d], 1);
        csr_src[pos] = src[i];
        csr_dst[pos] = d;
    }
}

// ---------------------------------------------------------------------------
// Pack W1 [1024,256] fp32 into bf16 MFMA-B fragment order.
__global__ void pack_w1(const float* __restrict__ W, ushort* __restrict__ Bp) {
    int o = blockIdx.x * blockDim.x + threadIdx.x;   // 0 .. 262143
    int j = o & 7;
    int lane = (o >> 3) & 63;
    int kchunk = (o >> 9) & 31;
    int ntile = o >> 14;
    int k = kchunk * 32 + (lane >> 4) * 8 + j;
    int n = ntile * 16 + (lane & 15);
    Bp[o] = f2bf(W[k * 256 + n]);
}

// Pack W2 [256,64] fp32 into bf16 MFMA-B fragment order (4 ntiles, 8 kchunks).
__global__ void pack_w2(const float* __restrict__ W, ushort* __restrict__ Bp) {
    int o = blockIdx.x * blockDim.x + threadIdx.x;   // 0 .. 16383
    int j = o & 7;
    int lane = (o >> 3) & 63;
    int kchunk = (o >> 9) & 7;
    int ntile = o >> 12;
    int k = kchunk * 32 + (lane >> 4) * 8 + j;
    int n = ntile * 16 + (lane & 15);
    Bp[o] = f2bf(W[k * 64 + n]);
}

// ---------------------------------------------------------------------------
// bf16 MFMA GEMM, layer 1: h1b[M,256](bf16) = A[M,1024](fp32) @ W1.
__global__ __launch_bounds__(256) void gemm1_mfma(const float* __restrict__ A,
                                                  const ushort* __restrict__ Bp,
                                                  ushort* __restrict__ C, int M) {
    __shared__ __align__(16) ushort Atile[128 * 32];   // 8 KB
    const int K = 1024, N = 256;
    int tid = threadIdx.x;
    int lane = tid & 63;
    int w = tid >> 6;
    int wm = w >> 1, wn = w & 1;
    int m0 = blockIdx.x * 128;
    int n0 = blockIdx.y * 128;

    const float* srow[4];
    int soff[4];
    #pragma unroll
    for (int l = 0; l < 4; ++l) {
        int slot = l * 256 + tid;
        int m = slot >> 3, hc = slot & 7;
        int c = hc >> 1;
        int row = m0 + m; if (row >= M) row = M - 1;
        srow[l] = A + (size_t)row * K + hc * 4;
        soff[l] = (m * 4 + (c ^ ((m >> 1) & 3))) * 8 + (hc & 1) * 4;
    }
    int afrag_off[4];
    #pragma unroll
    for (int mt = 0; mt < 4; ++mt) {
        int r = wm * 64 + mt * 16 + (lane & 15);
        int cq = lane >> 4;
        afrag_off[mt] = (r * 4 + (cq ^ ((r >> 1) & 3))) * 8;
    }
    const ushort* bbase[4];
    #pragma unroll
    for (int nt = 0; nt < 4; ++nt) {
        int ntile = blockIdx.y * 8 + wn * 4 + nt;
        bbase[nt] = Bp + ((size_t)(ntile * 32) * 64 + lane) * 8;
    }

    f32x4 acc[4][4] = {};

    for (int k0 = 0; k0 < K; k0 += 32) {
        #pragma unroll
        for (int l = 0; l < 4; ++l) {
            float4 v = *(const float4*)(srow[l] + k0);
            ushort4 b;
            b.x = f2bf(v.x); b.y = f2bf(v.y); b.z = f2bf(v.z); b.w = f2bf(v.w);
            *(ushort4*)&Atile[soff[l]] = b;
        }
        int kc = k0 >> 5;
        bf16x8 bfr[4];
        #pragma unroll
        for (int nt = 0; nt < 4; ++nt)
            bfr[nt] = *(const bf16x8*)(bbase[nt] + (size_t)kc * 64 * 8);
        __syncthreads();
        bf16x8 afr[4];
        #pragma unroll
        for (int mt = 0; mt < 4; ++mt)
            afr[mt] = *(const bf16x8*)&Atile[afrag_off[mt]];
        #pragma unroll
        for (int mt = 0; mt < 4; ++mt)
            #pragma unroll
            for (int nt = 0; nt < 4; ++nt)
                acc[mt][nt] = __builtin_amdgcn_mfma_f32_16x16x32_bf16(afr[mt], bfr[nt], acc[mt][nt], 0, 0, 0);
        __syncthreads();
    }
    #pragma unroll
    for (int mt = 0; mt < 4; ++mt) {
        #pragma unroll
        for (int nt = 0; nt < 4; ++nt) {
            int col = n0 + wn * 64 + nt * 16 + (lane & 15);
            #pragma unroll
            for (int r = 0; r < 4; ++r) {
                int row = m0 + wm * 64 + mt * 16 + (lane >> 4) * 4 + r;
                if (row < M) C[(size_t)row * N + col] = f2bf(acc[mt][nt][r]);
            }
        }
    }
}

// ---------------------------------------------------------------------------
// bf16 MFMA GEMM, layer 2: h2b[M,64](bf16) = x2b[M,256](bf16) @ W2.
__global__ __launch_bounds__(256) void gemm2_mfma(const ushort* __restrict__ Ab,
                                                  const ushort* __restrict__ Bp,
                                                  ushort* __restrict__ C, int M) {
    int tid = threadIdx.x;
    int lane = tid & 63;
    int w = tid >> 6;
    int m0 = blockIdx.x * 128 + w * 32;

    f32x4 acc[2][4] = {};
    #pragma unroll 2
    for (int kc = 0; kc < 8; ++kc) {
        bf16x8 afr[2];
        #pragma unroll
        for (int mt = 0; mt < 2; ++mt) {
            int r = m0 + mt * 16 + (lane & 15);
            if (r >= M) r = M - 1;
            afr[mt] = *(const bf16x8*)&Ab[(size_t)r * 256 + kc * 32 + (lane >> 4) * 8];
        }
        #pragma unroll
        for (int nt = 0; nt < 4; ++nt) {
            bf16x8 bfr = *(const bf16x8*)&Bp[((nt * 8 + kc) * 64 + lane) * 8];
            acc[0][nt] = __builtin_amdgcn_mfma_f32_16x16x32_bf16(afr[0], bfr, acc[0][nt], 0, 0, 0);
            acc[1][nt] = __builtin_amdgcn_mfma_f32_16x16x32_bf16(afr[1], bfr, acc[1][nt], 0, 0, 0);
        }
    }
    #pragma unroll
    for (int mt = 0; mt < 2; ++mt) {
        #pragma unroll
        for (int nt = 0; nt < 4; ++nt) {
            int col = nt * 16 + (lane & 15);
            #pragma unroll
            for (int r = 0; r < 4; ++r) {
                int row = m0 + mt * 16 + (lane >> 4) * 4 + r;
                if (row < M) C[(size_t)row * 64 + col] = f2bf(acc[mt][nt][r]);
            }
        }
    }
}

// ---------------------------------------------------------------------------
__device__ __forceinline__ float wave_reduce_sum(float v) {
    #pragma unroll
    for (int off = 32; off > 0; off >>= 1) v += __shfl_xor(v, off, 64);
    return v;
}

// logits from bf16 features. One wave per node; 4 nodes/block.
__global__ __launch_bounds__(256) void att_kernel(const ushort* __restrict__ h,
                                                  const float* __restrict__ asrc,
                                                  const float* __restrict__ adst,
                                                  float* __restrict__ al_s,
                                                  float* __restrict__ al_d,
                                                  int N, int H) {
    int lane = threadIdx.x & 63;
    int n = blockIdx.x * 4 + (threadIdx.x >> 6);
    if (n >= N) return;
    for (int hh = 0; hh < H; ++hh) {
        float hv = bf2f(h[(size_t)n * H * 64 + hh * 64 + lane]);
        float s = wave_reduce_sum(hv * asrc[hh * 64 + lane]);
        float d = wave_reduce_sum(hv * adst[hh * 64 + lane]);
        if (lane == 0) {
            al_s[n * H + hh] = s;
            al_d[n * H + hh] = d;
        }
    }
}

// Per-CSR-position softmax weights (no max subtraction: |logit| small here).
__global__ void edgew4_kernel(const float* __restrict__ als, const float* __restrict__ ald,
                              const int* __restrict__ csr_src, const int* __restrict__ csr_dst,
                              float* __restrict__ w, int E) {
    int p = blockIdx.x * blockDim.x + threadIdx.x;
    if (p >= E) return;
    int s = csr_src[p], d = csr_dst[p];
    float4 a = *(const float4*)&als[s * 4];
    float4 b = *(const float4*)&ald[d * 4];
    float4 o;
    float e;
    e = a.x + b.x; e = (e > 0.f) ? e : NEG_SLOPE * e; o.x = __expf(e);
    e = a.y + b.y; e = (e > 0.f) ? e : NEG_SLOPE * e; o.y = __expf(e);
    e = a.z + b.z; e = (e > 0.f) ? e : NEG_SLOPE * e; o.z = __expf(e);
    e = a.w + b.w; e = (e > 0.f) ? e : NEG_SLOPE * e; o.w = __expf(e);
    *(float4*)&w[p * 4] = o;
}

__global__ void edgew1_kernel(const float* __restrict__ als, const float* __restrict__ ald,
                              const int* __restrict__ csr_src, const int* __restrict__ csr_dst,
                              float* __restrict__ w, int E) {
    int p = blockIdx.x * blockDim.x + threadIdx.x;
    if (p >= E) return;
    float e = als[csr_src[p]] + ald[csr_dst[p]];
    e = (e > 0.f) ? e : NEG_SLOPE * e;
    w[p] = __expf(e);
}

// agg1: one node/block, 4 waves = 4 edge slices. Full 512-B row per wave.
__global__ __launch_bounds__(256) void agg1_kernel(const ushort* __restrict__ h,
                                                   const float* __restrict__ w,
                                                   const int* __restrict__ indptr,
                                                   const int* __restrict__ csr_src,
                                                   const float* __restrict__ bias,
                                                   ushort* __restrict__ out, int N) {
    __shared__ float4 lacc[4][64];
    __shared__ float  lden[4][64];
    int n = blockIdx.x;
    int lane = threadIdx.x & 63;
    int wv = threadIdx.x >> 6;
    int hd = lane >> 4;
    int beg = indptr[n], end = indptr[n + 1];
    float4 acc = make_float4(0.f, 0.f, 0.f, 0.f);
    float den = 0.f;
    int p = beg + wv;
    for (; p + 4 < end; p += 8) {
        int s0 = csr_src[p], s1 = csr_src[p + 4];
        float w0 = w[p * 4 + hd], w1 = w[(p + 4) * 4 + hd];
        ushort4 a0 = *(const ushort4*)&h[(size_t)s0 * 256 + lane * 4];
        ushort4 a1 = *(const ushort4*)&h[(size_t)s1 * 256 + lane * 4];
        acc.x = fmaf(w0, bf2f(a0.x), fmaf(w1, bf2f(a1.x), acc.x));
        acc.y = fmaf(w0, bf2f(a0.y), fmaf(w1, bf2f(a1.y), acc.y));
        acc.z = fmaf(w0, bf2f(a0.z), fmaf(w1, bf2f(a1.z), acc.z));
        acc.w = fmaf(w0, bf2f(a0.w), fmaf(w1, bf2f(a1.w), acc.w));
        den += w0 + w1;
    }
    if (p < end) {
        int s0 = csr_src[p];
        float w0 = w[p * 4 + hd];
        ushort4 a0 = *(const ushort4*)&h[(size_t)s0 * 256 + lane * 4];
        acc.x = fmaf(w0, bf2f(a0.x), acc.x);
        acc.y = fmaf(w0, bf2f(a0.y), acc.y);
        acc.z = fmaf(w0, bf2f(a0.z), acc.z);
        acc.w = fmaf(w0, bf2f(a0.w), acc.w);
        den += w0;
    }
    lacc[wv][lane] = acc;
    lden[wv][lane] = den;
    __syncthreads();
    if (wv == 0) {
        float4 a = lacc[0][lane];
        float4 a1 = lacc[1][lane], a2 = lacc[2][lane], a3 = lacc[3][lane];
        a.x += a1.x + a2.x + a3.x;
        a.y += a1.y + a2.y + a3.y;
        a.z += a1.z + a2.z + a3.z;
        a.w += a1.w + a2.w + a3.w;
        float d = lden[0][lane] + lden[1][lane] + lden[2][lane] + lden[3][lane];
        float4 bv = *(const float4*)&bias[lane * 4];
        float inv = 1.0f / d;
        float o0 = a.x * inv + bv.x, o1 = a.y * inv + bv.y;
        float o2 = a.z * inv + bv.z, o3 = a.w * inv + bv.w;
        o0 = (o0 > 0.f) ? o0 : (__expf(o0) - 1.0f);
        o1 = (o1 > 0.f) ? o1 : (__expf(o1) - 1.0f);
        o2 = (o2 > 0.f) ? o2 : (__expf(o2) - 1.0f);
        o3 = (o3 > 0.f) ? o3 : (__expf(o3) - 1.0f);
        ushort4 ob; ob.x = f2bf(o0); ob.y = f2bf(o1); ob.z = f2bf(o2); ob.w = f2bf(o3);
        *(ushort4*)&out[(size_t)n * 256 + lane * 4] = ob;
    }
}

// agg2: one node/block, 8 half-wave slices; 128-B row per half-wave.
__global__ __launch_bounds__(256) void agg2_kernel(const ushort* __restrict__ h,
                                                   const float* __restrict__ w,
                                                   const int* __restrict__ indptr,
                                                   const int* __restrict__ csr_src,
                                                   const float* __restrict__ bias,
                                                   float* __restrict__ out, int N) {
    __shared__ float2 lacc[8][32];
    __shared__ float  lden[8][32];
    int n = blockIdx.x;
    int lane = threadIdx.x & 63;
    int wv = threadIdx.x >> 6;
    int sl = wv * 2 + (lane >> 5);    // slice 0..7
    int l32 = lane & 31;
    int beg = indptr[n], end = indptr[n + 1];
    float2 acc = make_float2(0.f, 0.f);
    float den = 0.f;
    for (int p = beg + sl; p < end; p += 8) {
        int s = csr_src[p];
        float wt = w[p];
        ushort2 hv = *(const ushort2*)&h[(size_t)s * 64 + l32 * 2];
        acc.x = fmaf(wt, bf2f(hv.x), acc.x);
        acc.y = fmaf(wt, bf2f(hv.y), acc.y);
        den += wt;
    }
    lacc[sl][l32] = acc;
    lden[sl][l32] = den;
    __syncthreads();
    if (threadIdx.x < 32) {
        int c = threadIdx.x;
        float2 a = make_float2(0.f, 0.f);
        float d = 0.f;
        #pragma unroll
        for (int s = 0; s < 8; ++s) {
            a.x += lacc[s][c].x; a.y += lacc[s][c].y;
            d += lden[s][c];
        }
        float inv = 1.0f / d;
        float o0 = a.x * inv + bias[c * 2];
        float o1 = a.y * inv + bias[c * 2 + 1];
        o0 = (o0 > 0.f) ? o0 : (__expf(o0) - 1.0f);
        o1 = (o1 > 0.f) ? o1 : (__expf(o1) - 1.0f);
        *(float2*)&out[(size_t)n * 64 + c * 2] = make_float2(o0, o1);
    }
}

// Fused mean-pool + FC: one block per graph. batch is SORTED, so graph g owns
// a contiguous node range found by binary search. No atomics.
__global__ __launch_bounds__(256) void pool_fc_kernel(const float* __restrict__ hfin,
                                                      const int* __restrict__ batch,
                                                      const float* __restrict__ fc_w,
                                                      const float* __restrict__ fc_b,
                                                      float* __restrict__ out, int N) {
    __shared__ float lacc[4][64];
    int g = blockIdx.x;
    // lower_bound(batch, g) and lower_bound(batch, g+1) — redundant per-thread
    int beg, end;
    {
        int lo = 0, hi = N;
        while (lo < hi) { int mid = (lo + hi) >> 1; if (batch[mid] < g) lo = mid + 1; else hi = mid; }
        beg = lo;
        lo = beg; hi = N;
        while (lo < hi) { int mid = (lo + hi) >> 1; if (batch[mid] < g + 1) lo = mid + 1; else hi = mid; }
        end = lo;
    }
    int lane = threadIdx.x & 63;
    int wv = threadIdx.x >> 6;
    float acc = 0.f;
    for (int n = beg + wv; n < end; n += 4)
        acc += hfin[(size_t)n * 64 + lane];
    lacc[wv][lane] = acc;
    __syncthreads();
    if (wv == 0) {
        float s = lacc[0][lane] + lacc[1][lane] + lacc[2][lane] + lacc[3][lane];
        float cnt = fmaxf((float)(end - beg), 1.0f);
        float pooled = s / cnt;
        float p0 = wave_reduce_sum(pooled * fc_w[lane * 2 + 0]);
        float p1 = wave_reduce_sum(pooled * fc_w[lane * 2 + 1]);
        if (lane == 0) {
            out[g * 2 + 0] = p0 + fc_b[0];
            out[g * 2 + 1] = p1 + fc_b[1];
        }
    }
}

// ---------------------------------------------------------------------------
extern "C" void kernel_launch(void* const* d_in, const int* in_sizes, int n_in,
                              void* d_out, int out_size, void* d_ws, size_t ws_size,
                              hipStream_t stream) {
    const float* x      = (const float*)d_in[0];
    const int*   ei     = (const int*)d_in[1];
    const int*   batch  = (const int*)d_in[2];
    const float* W1     = (const float*)d_in[3];
    const float* asrc1  = (const float*)d_in[4];
    const float* adst1  = (const float*)d_in[5];
    const float* b1     = (const float*)d_in[6];
    const float* W2     = (const float*)d_in[7];
    const float* asrc2  = (const float*)d_in[8];
    const float* adst2  = (const float*)d_in[9];
    const float* b2     = (const float*)d_in[10];
    const float* fc_w   = (const float*)d_in[11];
    const float* fc_b   = (const float*)d_in[12];
    float* out          = (float*)d_out;

    const int N = in_sizes[2];          // 50000
    const int E = in_sizes[1] / 2;      // 850000
    const int* src = ei;
    const int* dst = ei + E;

    float* ws = (float*)d_ws;
    int*    counts  = (int*)(ws + WS_COUNTS);
    int*    indptr  = (int*)(ws + WS_INDPTR);
    int*    cursor  = (int*)(ws + WS_CURSOR);
    int*    csr_src = (int*)(ws + WS_CSRSRC);
    int*    csr_dst = (int*)(ws + WS_CSRDST);
    int*    bsum    = (int*)(ws + WS_BSUM);
    float*  al_s1   = ws + WS_ALS1;
    float*  al_d1   = ws + WS_ALD1;
    float*  al_s2   = ws + WS_ALS2;
    float*  al_d2   = ws + WS_ALD2;
    ushort* bp      = (ushort*)(ws + WS_BP);
    ushort* bp2     = (ushort*)(ws + WS_BP2);
    ushort* h1b     = (ushort*)(ws + WS_H1B);
    ushort* x2b     = (ushort*)(ws + WS_X2B);
    ushort* h2b     = (ushort*)(ws + WS_H2B);
    float*  w1e     = ws + WS_W1E;
    float*  w2e     = ws + WS_W1E;    // alias (w1e dead before edgew1_kernel)
    float*  hfin    = ws + WS_HFIN;

    const int nb = (N + 1023) / 1024;   // scan blocks (<=64)

    // 1. zero counts; pack weights to bf16 fragment order
    zero_kernel<<<(WS_ZEROLEN + 255) / 256, 256, 0, stream>>>(ws, WS_ZEROLEN);
    pack_w1<<<(INDIM * F1) / 256, 256, 0, stream>>>(W1, bp);
    pack_w2<<<(F1 * HIDC) / 256, 256, 0, stream>>>(W2, bp2);
    // 2. CSR build (by dst)
    hist_kernel<<<(E + 255) / 256, 256, 0, stream>>>(dst, counts, E);
    scan1_kernel<<<nb, 1024, 0, stream>>>(counts, indptr, bsum, N);
    scan2_kernel<<<1, 64, 0, stream>>>(bsum, nb);
    scan3_kernel<<<nb, 1024, 0, stream>>>(counts, indptr, cursor, bsum, N);
    fill_kernel<<<(E + 255) / 256, 256, 0, stream>>>(src, dst, cursor, csr_src, csr_dst, E);
    // 3. layer 1 GEMM -> h1b (bf16)
    gemm1_mfma<<<dim3((N + 127) / 128, F1 / 128), 256, 0, stream>>>(x, bp, h1b, N);
    // 4. attention logits + per-edge softmax weights
    att_kernel<<<(N + 3) / 4, 256, 0, stream>>>(h1b, asrc1, adst1, al_s1, al_d1, N, HEADS1);
    edgew4_kernel<<<(E + 255) / 256, 256, 0, stream>>>(al_s1, al_d1, csr_src, csr_dst, w1e, E);
    // 5. aggregate + bias + ELU -> x2b (bf16)
    agg1_kernel<<<N, 256, 0, stream>>>(h1b, w1e, indptr, csr_src, b1, x2b, N);
    // 6. layer 2 GEMM -> h2b (bf16)
    gemm2_mfma<<<(N + 127) / 128, 256, 0, stream>>>(x2b, bp2, h2b, N);
    // 7. attention logits + weights layer 2
    att_kernel<<<(N + 3) / 4, 256, 0, stream>>>(h2b, asrc2, adst2, al_s2, al_d2, N, 1);
    edgew1_kernel<<<(E + 255) / 256, 256, 0, stream>>>(al_s2, al_d2, csr_src, csr_dst, w2e, E);
    // 8. aggregate + bias + ELU -> hfin (fp32)
    agg2_kernel<<<N, 256, 0, stream>>>(h2b, w2e, indptr, csr_src, b2, hfin, N);
    // 9. fused mean pool + FC (batch sorted => contiguous ranges, no atomics)
    pool_fc_kernel<<<NGRAPHS, 256, 0, stream>>>(hfin, batch, fc_w, fc_b, out, N);
}

// Round 6
// 668.131 us; speedup vs baseline: 2.6248x; 1.0529x over previous
//
#include <hip/hip_runtime.h>
#include <hip/hip_bf16.h>

// Problem constants (fixed by the reference setup)
#define NNODES   50000
#define NGRAPHS  64
#define INDIM    1024
#define HIDC     64      // channels per head
#define HEADS1   4
#define F1       (HEADS1*HIDC)   // 256
#define NEG_SLOPE 0.2f

// ---------------------------------------------------------------------------
// Workspace layout (4-byte words). All vector-accessed buffers 16B-aligned.
#define WS_COUNTS   0                    // int[50000]
#define WS_ZEROLEN  50000                // words to zero (counts only)
#define WS_INDPTR   54208                // int[50001]
#define WS_CURSOR   104256               // int[50000]
#define WS_CSRSRC   154304               // int[850000]
#define WS_CSRDST   1004304              // int[850000]
#define WS_BSUM     1854304              // int[64]
#define WS_ALS1     1854368              // float[200000]
#define WS_ALD1     2054368              // float[200000]
#define WS_ALS2     2254368              // float[50000]
#define WS_ALD2     2304368              // float[50000]
#define WS_BP       2354368              // ushort[262144] (packed bf16 W1)
#define WS_BP2      2485440              // ushort[16384]  (packed bf16 W2)
#define WS_H1B      2493632              // ushort[12,800,000] bf16 h1
#define WS_X2B      8893632              // ushort[12,800,000] bf16 x2
#define WS_H2B      15293632             // ushort[3,200,000]  bf16 h2
#define WS_HFIN     16893632             // float[3,200,000]

typedef __attribute__((ext_vector_type(8))) short bf16x8;
typedef __attribute__((ext_vector_type(4))) float f32x4;

__device__ __forceinline__ ushort f2bf(float f) {
    union { float f; uint u; } v; v.f = f;
    uint r = v.u + 0x7fff + ((v.u >> 16) & 1);   // round-to-nearest-even
    return (ushort)(r >> 16);
}
__device__ __forceinline__ float bf2f(ushort u) {
    union { uint u; float f; } v; v.u = (uint)u << 16; return v.f;
}

// ---------------------------------------------------------------------------
__global__ void zero_kernel(float* p, int n) {
    int i = blockIdx.x * blockDim.x + threadIdx.x;
    if (i < n) p[i] = 0.0f;
}

__global__ void hist_kernel(const int* __restrict__ dst, int* __restrict__ counts, int E) {
    int i = blockIdx.x * blockDim.x + threadIdx.x;
    if (i < E) atomicAdd(&counts[dst[i]], 1);
}

// --- 3-kernel multi-block scan -------------------------------------------
__global__ __launch_bounds__(1024) void scan1_kernel(const int* __restrict__ counts,
                                                     int* __restrict__ indptr,
                                                     int* __restrict__ bsum, int N) {
    __shared__ int sm[1024];
    int b = blockIdx.x;
    int i = b * 1024 + (int)threadIdx.x;
    int v = (i < N) ? counts[i] : 0;
    sm[threadIdx.x] = v;
    __syncthreads();
    for (int off = 1; off < 1024; off <<= 1) {
        int t = (threadIdx.x >= (unsigned)off) ? sm[threadIdx.x - off] : 0;
        __syncthreads();
        sm[threadIdx.x] += t;
        __syncthreads();
    }
    if (i < N) indptr[i + 1] = sm[threadIdx.x];
    if (threadIdx.x == 1023) bsum[b] = sm[1023];
}

__global__ void scan2_kernel(int* __restrict__ bsum, int nb) {
    int lane = threadIdx.x;
    int v = (lane < nb) ? bsum[lane] : 0;
    int orig = v;
    #pragma unroll
    for (int off = 1; off < 64; off <<= 1) {
        int t = __shfl_up(v, off, 64);
        if (lane >= off) v += t;
    }
    if (lane < nb) bsum[lane] = v - orig;   // exclusive
}

__global__ __launch_bounds__(1024) void scan3_kernel(const int* __restrict__ counts,
                                                     int* __restrict__ indptr,
                                                     int* __restrict__ cursor,
                                                     const int* __restrict__ bsum, int N) {
    int i = blockIdx.x * 1024 + (int)threadIdx.x;
    if (i == 0) indptr[0] = 0;
    if (i < N) {
        int incl = indptr[i + 1] + bsum[blockIdx.x];
        indptr[i + 1] = incl;
        cursor[i] = incl - counts[i];
    }
}

__global__ void fill_kernel(const int* __restrict__ src, const int* __restrict__ dst,
                            int* __restrict__ cursor, int* __restrict__ csr_src,
                            int* __restrict__ csr_dst, int E) {
    int i = blockIdx.x * blockDim.x + threadIdx.x;
    if (i < E) {
        int d = dst[i];
        int pos = atomicAdd(&cursor[d], 1);
        csr_src[pos] = src[i];
        csr_dst[pos] = d;
    }
}

// ---------------------------------------------------------------------------
// Pack W1 [1024,256] fp32 into bf16 MFMA-B fragment order.
__global__ void pack_w1(const float* __restrict__ W, ushort* __restrict__ Bp) {
    int o = blockIdx.x * blockDim.x + threadIdx.x;   // 0 .. 262143
    int j = o & 7;
    int lane = (o >> 3) & 63;
    int kchunk = (o >> 9) & 31;
    int ntile = o >> 14;
    int k = kchunk * 32 + (lane >> 4) * 8 + j;
    int n = ntile * 16 + (lane & 15);
    Bp[o] = f2bf(W[k * 256 + n]);
}

// Pack W2 [256,64] fp32 into bf16 MFMA-B fragment order (4 ntiles, 8 kchunks).
__global__ void pack_w2(const float* __restrict__ W, ushort* __restrict__ Bp) {
    int o = blockIdx.x * blockDim.x + threadIdx.x;   // 0 .. 16383
    int j = o & 7;
    int lane = (o >> 3) & 63;
    int kchunk = (o >> 9) & 7;
    int ntile = o >> 12;
    int k = kchunk * 32 + (lane >> 4) * 8 + j;
    int n = ntile * 16 + (lane & 15);
    Bp[o] = f2bf(W[k * 64 + n]);
}

// ---------------------------------------------------------------------------
// bf16 MFMA GEMM, layer 1: h1b[M,256](bf16) = A[M,1024](fp32) @ W1.
// Double-buffered LDS (one barrier/iter; staging loads for k+1 in flight
// during MFMA of k). Epilogue fuses attention logits als1/ald1.
__global__ __launch_bounds__(256) void gemm1_mfma(const float* __restrict__ A,
                                                  const ushort* __restrict__ Bp,
                                                  ushort* __restrict__ C,
                                                  const float* __restrict__ asrc,
                                                  const float* __restrict__ adst,
                                                  float* __restrict__ als,
                                                  float* __restrict__ ald,
                                                  int M) {
    __shared__ __align__(16) ushort Atile[2][128 * 32];   // 2 x 8 KB
    const int K = 1024, N = 256;
    int tid = threadIdx.x;
    int lane = tid & 63;
    int w = tid >> 6;
    int wm = w >> 1, wn = w & 1;
    int m0 = blockIdx.x * 128;
    int n0 = blockIdx.y * 128;

    const float* srow[4];
    int soff[4];
    #pragma unroll
    for (int l = 0; l < 4; ++l) {
        int slot = l * 256 + tid;
        int m = slot >> 3, hc = slot & 7;
        int c = hc >> 1;
        int row = m0 + m; if (row >= M) row = M - 1;
        srow[l] = A + (size_t)row * K + hc * 4;
        soff[l] = (m * 4 + (c ^ ((m >> 1) & 3))) * 8 + (hc & 1) * 4;
    }
    int afrag_off[4];
    #pragma unroll
    for (int mt = 0; mt < 4; ++mt) {
        int r = wm * 64 + mt * 16 + (lane & 15);
        int cq = lane >> 4;
        afrag_off[mt] = (r * 4 + (cq ^ ((r >> 1) & 3))) * 8;
    }
    const ushort* bbase[4];
    #pragma unroll
    for (int nt = 0; nt < 4; ++nt) {
        int ntile = blockIdx.y * 8 + wn * 4 + nt;
        bbase[nt] = Bp + ((size_t)(ntile * 32) * 64 + lane) * 8;
    }

    f32x4 acc[4][4] = {};
    float4 v[4];
    #pragma unroll
    for (int l = 0; l < 4; ++l) v[l] = *(const float4*)(srow[l]);

    for (int kc = 0; kc < 32; ++kc) {
        ushort* At = Atile[kc & 1];
        #pragma unroll
        for (int l = 0; l < 4; ++l) {
            ushort4 b;
            b.x = f2bf(v[l].x); b.y = f2bf(v[l].y);
            b.z = f2bf(v[l].z); b.w = f2bf(v[l].w);
            *(ushort4*)&At[soff[l]] = b;
        }
        if (kc < 31) {
            #pragma unroll
            for (int l = 0; l < 4; ++l)
                v[l] = *(const float4*)(srow[l] + (kc + 1) * 32);
        }
        bf16x8 bfr[4];
        #pragma unroll
        for (int nt = 0; nt < 4; ++nt)
            bfr[nt] = *(const bf16x8*)(bbase[nt] + (size_t)kc * 64 * 8);
        __syncthreads();
        bf16x8 afr[4];
        #pragma unroll
        for (int mt = 0; mt < 4; ++mt)
            afr[mt] = *(const bf16x8*)&At[afrag_off[mt]];
        #pragma unroll
        for (int mt = 0; mt < 4; ++mt)
            #pragma unroll
            for (int nt = 0; nt < 4; ++nt)
                acc[mt][nt] = __builtin_amdgcn_mfma_f32_16x16x32_bf16(afr[mt], bfr[nt], acc[mt][nt], 0, 0, 0);
    }

    // epilogue: C write (bf16) + fused attention logits for this wave's head
    int head = blockIdx.y * 2 + wn;
    float a_s[4], a_d[4];
    #pragma unroll
    for (int nt = 0; nt < 4; ++nt) {
        a_s[nt] = asrc[head * 64 + nt * 16 + (lane & 15)];
        a_d[nt] = adst[head * 64 + nt * 16 + (lane & 15)];
    }
    #pragma unroll
    for (int mt = 0; mt < 4; ++mt) {
        #pragma unroll
        for (int nt = 0; nt < 4; ++nt) {
            int col = n0 + wn * 64 + nt * 16 + (lane & 15);
            #pragma unroll
            for (int r = 0; r < 4; ++r) {
                int row = m0 + wm * 64 + mt * 16 + (lane >> 4) * 4 + r;
                if (row < M) C[(size_t)row * N + col] = f2bf(acc[mt][nt][r]);
            }
        }
        #pragma unroll
        for (int r = 0; r < 4; ++r) {
            int row = m0 + wm * 64 + mt * 16 + (lane >> 4) * 4 + r;
            float s = 0.f, d = 0.f;
            #pragma unroll
            for (int nt = 0; nt < 4; ++nt) {
                float c = acc[mt][nt][r];
                s = fmaf(c, a_s[nt], s);
                d = fmaf(c, a_d[nt], d);
            }
            #pragma unroll
            for (int off = 1; off < 16; off <<= 1) {
                s += __shfl_xor(s, off, 64);
                d += __shfl_xor(d, off, 64);
            }
            if ((lane & 15) == 0 && row < M) {
                als[row * 4 + head] = s;
                ald[row * 4 + head] = d;
            }
        }
    }
}

// ---------------------------------------------------------------------------
// bf16 MFMA GEMM, layer 2: h2b[M,64](bf16) = x2b[M,256](bf16) @ W2.
// Epilogue fuses attention logits als2/ald2 (single head).
__global__ __launch_bounds__(256) void gemm2_mfma(const ushort* __restrict__ Ab,
                                                  const ushort* __restrict__ Bp,
                                                  ushort* __restrict__ C,
                                                  const float* __restrict__ asrc,
                                                  const float* __restrict__ adst,
                                                  float* __restrict__ als,
                                                  float* __restrict__ ald,
                                                  int M) {
    int tid = threadIdx.x;
    int lane = tid & 63;
    int w = tid >> 6;
    int m0 = blockIdx.x * 128 + w * 32;

    f32x4 acc[2][4] = {};
    #pragma unroll 2
    for (int kc = 0; kc < 8; ++kc) {
        bf16x8 afr[2];
        #pragma unroll
        for (int mt = 0; mt < 2; ++mt) {
            int r = m0 + mt * 16 + (lane & 15);
            if (r >= M) r = M - 1;
            afr[mt] = *(const bf16x8*)&Ab[(size_t)r * 256 + kc * 32 + (lane >> 4) * 8];
        }
        #pragma unroll
        for (int nt = 0; nt < 4; ++nt) {
            bf16x8 bfr = *(const bf16x8*)&Bp[((nt * 8 + kc) * 64 + lane) * 8];
            acc[0][nt] = __builtin_amdgcn_mfma_f32_16x16x32_bf16(afr[0], bfr, acc[0][nt], 0, 0, 0);
            acc[1][nt] = __builtin_amdgcn_mfma_f32_16x16x32_bf16(afr[1], bfr, acc[1][nt], 0, 0, 0);
        }
    }
    float a_s[4], a_d[4];
    #pragma unroll
    for (int nt = 0; nt < 4; ++nt) {
        a_s[nt] = asrc[nt * 16 + (lane & 15)];
        a_d[nt] = adst[nt * 16 + (lane & 15)];
    }
    #pragma unroll
    for (int mt = 0; mt < 2; ++mt) {
        #pragma unroll
        for (int nt = 0; nt < 4; ++nt) {
            int col = nt * 16 + (lane & 15);
            #pragma unroll
            for (int r = 0; r < 4; ++r) {
                int row = m0 + mt * 16 + (lane >> 4) * 4 + r;
                if (row < M) C[(size_t)row * 64 + col] = f2bf(acc[mt][nt][r]);
            }
        }
        #pragma unroll
        for (int r = 0; r < 4; ++r) {
            int row = m0 + mt * 16 + (lane >> 4) * 4 + r;
            float s = 0.f, d = 0.f;
            #pragma unroll
            for (int nt = 0; nt < 4; ++nt) {
                float c = acc[mt][nt][r];
                s = fmaf(c, a_s[nt], s);
                d = fmaf(c, a_d[nt], d);
            }
            #pragma unroll
            for (int off = 1; off < 16; off <<= 1) {
                s += __shfl_xor(s, off, 64);
                d += __shfl_xor(d, off, 64);
            }
            if ((lane & 15) == 0 && row < M) {
                als[row] = s;
                ald[row] = d;
            }
        }
    }
}

// ---------------------------------------------------------------------------
__device__ __forceinline__ float wave_reduce_sum(float v) {
    #pragma unroll
    for (int off = 32; off > 0; off >>= 1) v += __shfl_xor(v, off, 64);
    return v;
}

__device__ __forceinline__ float edge_w(float e) {
    e = (e > 0.f) ? e : NEG_SLOPE * e;
    return __expf(e);
}

// agg1: one node/block, 4 waves = 4 edge slices. Full 512-B row per wave.
// Softmax weights computed inline from als/ald (no w array).
__global__ __launch_bounds__(256) void agg1_kernel(const ushort* __restrict__ h,
                                                   const float* __restrict__ als,
                                                   const float* __restrict__ ald,
                                                   const int* __restrict__ indptr,
                                                   const int* __restrict__ csr_src,
                                                   const float* __restrict__ bias,
                                                   ushort* __restrict__ out, int N) {
    __shared__ float4 lacc[4][64];
    __shared__ float  lden[4][64];
    int n = blockIdx.x;
    int lane = threadIdx.x & 63;
    int wv = threadIdx.x >> 6;
    int hd = lane >> 4;
    int beg = indptr[n], end = indptr[n + 1];
    float ald_h = ald[n * 4 + hd];
    float4 acc = make_float4(0.f, 0.f, 0.f, 0.f);
    float den = 0.f;
    int p = beg + wv;
    for (; p + 4 < end; p += 8) {
        int s0 = csr_src[p], s1 = csr_src[p + 4];
        float w0 = edge_w(als[s0 * 4 + hd] + ald_h);
        float w1 = edge_w(als[s1 * 4 + hd] + ald_h);
        ushort4 a0 = *(const ushort4*)&h[(size_t)s0 * 256 + lane * 4];
        ushort4 a1 = *(const ushort4*)&h[(size_t)s1 * 256 + lane * 4];
        acc.x = fmaf(w0, bf2f(a0.x), fmaf(w1, bf2f(a1.x), acc.x));
        acc.y = fmaf(w0, bf2f(a0.y), fmaf(w1, bf2f(a1.y), acc.y));
        acc.z = fmaf(w0, bf2f(a0.z), fmaf(w1, bf2f(a1.z), acc.z));
        acc.w = fmaf(w0, bf2f(a0.w), fmaf(w1, bf2f(a1.w), acc.w));
        den += w0 + w1;
    }
    if (p < end) {
        int s0 = csr_src[p];
        float w0 = edge_w(als[s0 * 4 + hd] + ald_h);
        ushort4 a0 = *(const ushort4*)&h[(size_t)s0 * 256 + lane * 4];
        acc.x = fmaf(w0, bf2f(a0.x), acc.x);
        acc.y = fmaf(w0, bf2f(a0.y), acc.y);
        acc.z = fmaf(w0, bf2f(a0.z), acc.z);
        acc.w = fmaf(w0, bf2f(a0.w), acc.w);
        den += w0;
    }
    lacc[wv][lane] = acc;
    lden[wv][lane] = den;
    __syncthreads();
    if (wv == 0) {
        float4 a = lacc[0][lane];
        float4 a1 = lacc[1][lane], a2 = lacc[2][lane], a3 = lacc[3][lane];
        a.x += a1.x + a2.x + a3.x;
        a.y += a1.y + a2.y + a3.y;
        a.z += a1.z + a2.z + a3.z;
        a.w += a1.w + a2.w + a3.w;
        float d = lden[0][lane] + lden[1][lane] + lden[2][lane] + lden[3][lane];
        float4 bv = *(const float4*)&bias[lane * 4];
        float inv = 1.0f / d;
        float o0 = a.x * inv + bv.x, o1 = a.y * inv + bv.y;
        float o2 = a.z * inv + bv.z, o3 = a.w * inv + bv.w;
        o0 = (o0 > 0.f) ? o0 : (__expf(o0) - 1.0f);
        o1 = (o1 > 0.f) ? o1 : (__expf(o1) - 1.0f);
        o2 = (o2 > 0.f) ? o2 : (__expf(o2) - 1.0f);
        o3 = (o3 > 0.f) ? o3 : (__expf(o3) - 1.0f);
        ushort4 ob; ob.x = f2bf(o0); ob.y = f2bf(o1); ob.z = f2bf(o2); ob.w = f2bf(o3);
        *(ushort4*)&out[(size_t)n * 256 + lane * 4] = ob;
    }
}

// agg2: one node/block, 8 half-wave slices; 128-B row per half-wave.
__global__ __launch_bounds__(256) void agg2_kernel(const ushort* __restrict__ h,
                                                   const float* __restrict__ als,
                                                   const float* __restrict__ ald,
                                                   const int* __restrict__ indptr,
                                                   const int* __restrict__ csr_src,
                                                   const float* __restrict__ bias,
                                                   float* __restrict__ out, int N) {
    __shared__ float2 lacc[8][32];
    __shared__ float  lden[8][32];
    int n = blockIdx.x;
    int lane = threadIdx.x & 63;
    int wv = threadIdx.x >> 6;
    int sl = wv * 2 + (lane >> 5);    // slice 0..7
    int l32 = lane & 31;
    int beg = indptr[n], end = indptr[n + 1];
    float ald_n = ald[n];
    float2 acc = make_float2(0.f, 0.f);
    float den = 0.f;
    for (int p = beg + sl; p < end; p += 8) {
        int s = csr_src[p];
        float wt = edge_w(als[s] + ald_n);
        ushort2 hv = *(const ushort2*)&h[(size_t)s * 64 + l32 * 2];
        acc.x = fmaf(wt, bf2f(hv.x), acc.x);
        acc.y = fmaf(wt, bf2f(hv.y), acc.y);
        den += wt;
    }
    lacc[sl][l32] = acc;
    lden[sl][l32] = den;
    __syncthreads();
    if (threadIdx.x < 32) {
        int c = threadIdx.x;
        float2 a = make_float2(0.f, 0.f);
        float d = 0.f;
        #pragma unroll
        for (int s = 0; s < 8; ++s) {
            a.x += lacc[s][c].x; a.y += lacc[s][c].y;
            d += lden[s][c];
        }
        float inv = 1.0f / d;
        float o0 = a.x * inv + bias[c * 2];
        float o1 = a.y * inv + bias[c * 2 + 1];
        o0 = (o0 > 0.f) ? o0 : (__expf(o0) - 1.0f);
        o1 = (o1 > 0.f) ? o1 : (__expf(o1) - 1.0f);
        *(float2*)&out[(size_t)n * 64 + c * 2] = make_float2(o0, o1);
    }
}

// Fused mean-pool + FC: one block per graph (batch sorted => contiguous range).
__global__ __launch_bounds__(256) void pool_fc_kernel(const float* __restrict__ hfin,
                                                      const int* __restrict__ batch,
                                                      const float* __restrict__ fc_w,
                                                      const float* __restrict__ fc_b,
                                                      float* __restrict__ out, int N) {
    __shared__ float lacc[4][64];
    int g = blockIdx.x;
    int beg, end;
    {
        int lo = 0, hi = N;
        while (lo < hi) { int mid = (lo + hi) >> 1; if (batch[mid] < g) lo = mid + 1; else hi = mid; }
        beg = lo;
        lo = beg; hi = N;
        while (lo < hi) { int mid = (lo + hi) >> 1; if (batch[mid] < g + 1) lo = mid + 1; else hi = mid; }
        end = lo;
    }
    int lane = threadIdx.x & 63;
    int wv = threadIdx.x >> 6;
    float acc = 0.f;
    for (int n = beg + wv; n < end; n += 4)
        acc += hfin[(size_t)n * 64 + lane];
    lacc[wv][lane] = acc;
    __syncthreads();
    if (wv == 0) {
        float s = lacc[0][lane] + lacc[1][lane] + lacc[2][lane] + lacc[3][lane];
        float cnt = fmaxf((float)(end - beg), 1.0f);
        float pooled = s / cnt;
        float p0 = wave_reduce_sum(pooled * fc_w[lane * 2 + 0]);
        float p1 = wave_reduce_sum(pooled * fc_w[lane * 2 + 1]);
        if (lane == 0) {
            out[g * 2 + 0] = p0 + fc_b[0];
            out[g * 2 + 1] = p1 + fc_b[1];
        }
    }
}

// ---------------------------------------------------------------------------
extern "C" void kernel_launch(void* const* d_in, const int* in_sizes, int n_in,
                              void* d_out, int out_size, void* d_ws, size_t ws_size,
                              hipStream_t stream) {
    const float* x      = (const float*)d_in[0];
    const int*   ei     = (const int*)d_in[1];
    const int*   batch  = (const int*)d_in[2];
    const float* W1     = (const float*)d_in[3];
    const float* asrc1  = (const float*)d_in[4];
    const float* adst1  = (const float*)d_in[5];
    const float* b1     = (const float*)d_in[6];
    const float* W2     = (const float*)d_in[7];
    const float* asrc2  = (const float*)d_in[8];
    const float* adst2  = (const float*)d_in[9];
    const float* b2     = (const float*)d_in[10];
    const float* fc_w   = (const float*)d_in[11];
    const float* fc_b   = (const float*)d_in[12];
    float* out          = (float*)d_out;

    const int N = in_sizes[2];          // 50000
    const int E = in_sizes[1] / 2;      // 850000
    const int* src = ei;
    const int* dst = ei + E;

    float* ws = (float*)d_ws;
    int*    counts  = (int*)(ws + WS_COUNTS);
    int*    indptr  = (int*)(ws + WS_INDPTR);
    int*    cursor  = (int*)(ws + WS_CURSOR);
    int*    csr_src = (int*)(ws + WS_CSRSRC);
    int*    csr_dst = (int*)(ws + WS_CSRDST);
    int*    bsum    = (int*)(ws + WS_BSUM);
    float*  al_s1   = ws + WS_ALS1;
    float*  al_d1   = ws + WS_ALD1;
    float*  al_s2   = ws + WS_ALS2;
    float*  al_d2   = ws + WS_ALD2;
    ushort* bp      = (ushort*)(ws + WS_BP);
    ushort* bp2     = (ushort*)(ws + WS_BP2);
    ushort* h1b     = (ushort*)(ws + WS_H1B);
    ushort* x2b     = (ushort*)(ws + WS_X2B);
    ushort* h2b     = (ushort*)(ws + WS_H2B);
    float*  hfin    = ws + WS_HFIN;

    const int nb = (N + 1023) / 1024;   // scan blocks (<=64)

    // 1. zero counts; pack weights to bf16 fragment order
    zero_kernel<<<(WS_ZEROLEN + 255) / 256, 256, 0, stream>>>(ws, WS_ZEROLEN);
    pack_w1<<<(INDIM * F1) / 256, 256, 0, stream>>>(W1, bp);
    pack_w2<<<(F1 * HIDC) / 256, 256, 0, stream>>>(W2, bp2);
    // 2. CSR build (by dst)
    hist_kernel<<<(E + 255) / 256, 256, 0, stream>>>(dst, counts, E);
    scan1_kernel<<<nb, 1024, 0, stream>>>(counts, indptr, bsum, N);
    scan2_kernel<<<1, 64, 0, stream>>>(bsum, nb);
    scan3_kernel<<<nb, 1024, 0, stream>>>(counts, indptr, cursor, bsum, N);
    fill_kernel<<<(E + 255) / 256, 256, 0, stream>>>(src, dst, cursor, csr_src, csr_dst, E);
    // 3. layer 1 GEMM (dbuf) -> h1b (bf16) + fused att logits
    gemm1_mfma<<<dim3((N + 127) / 128, F1 / 128), 256, 0, stream>>>(
        x, bp, h1b, asrc1, adst1, al_s1, al_d1, N);
    // 4. aggregate (inline softmax weights) + bias + ELU -> x2b (bf16)
    agg1_kernel<<<N, 256, 0, stream>>>(h1b, al_s1, al_d1, indptr, csr_src, b1, x2b, N);
    // 5. layer 2 GEMM -> h2b (bf16) + fused att logits
    gemm2_mfma<<<(N + 127) / 128, 256, 0, stream>>>(
        x2b, bp2, h2b, asrc2, adst2, al_s2, al_d2, N);
    // 6. aggregate (inline softmax weights) + bias + ELU -> hfin (fp32)
    agg2_kernel<<<N, 256, 0, stream>>>(h2b, al_s2, al_d2, indptr, csr_src, b2, hfin, N);
    // 7. fused mean pool + FC
    pool_fc_kernel<<<NGRAPHS, 256, 0, stream>>>(hfin, batch, fc_w, fc_b, out, N);
}

// Round 7
// 647.678 us; speedup vs baseline: 2.7077x; 1.0316x over previous
//
#include <hip/hip_runtime.h>
#include <hip/hip_bf16.h>

// Problem constants (fixed by the reference setup)
#define NNODES   50000
#define NGRAPHS  64
#define INDIM    1024
#define HIDC     64      // channels per head
#define HEADS1   4
#define F1       (HEADS1*HIDC)   // 256
#define NEG_SLOPE 0.2f

// ---------------------------------------------------------------------------
// Workspace layout (4-byte words). All vector-accessed buffers 16B-aligned.
#define WS_COUNTS   0                    // int[50000]
#define WS_ZEROLEN  50000                // words to zero (counts only)
#define WS_INDPTR   54208                // int[50001]
#define WS_CURSOR   104256               // int[50000]
#define WS_CSRSRC   154304               // int[850000]
#define WS_CSRDST   1004304              // int[850000]
#define WS_BSUM     1854304              // int[64]
#define WS_ALS1     1854368              // float[200000]
#define WS_ALD1     2054368              // float[200000]
#define WS_ALS2     2254368              // float[50000]
#define WS_ALD2     2304368              // float[50000]
#define WS_BP       2354368              // ushort[262144] (packed bf16 W1)
#define WS_BP2      2485440              // ushort[16384]  (packed bf16 W2)
#define WS_H1B      2493632              // ushort[12,800,000] bf16 h1
#define WS_X2B      8893632              // ushort[12,800,000] bf16 x2
#define WS_H2B      15293632             // ushort[3,200,000]  bf16 h2
#define WS_HFIN     16893632             // float[3,200,000]

typedef __attribute__((ext_vector_type(8))) short bf16x8;
typedef __attribute__((ext_vector_type(4))) float f32x4;

__device__ __forceinline__ ushort f2bf(float f) {
    union { float f; uint u; } v; v.f = f;
    uint r = v.u + 0x7fff + ((v.u >> 16) & 1);   // round-to-nearest-even
    return (ushort)(r >> 16);
}
__device__ __forceinline__ float bf2f(ushort u) {
    union { uint u; float f; } v; v.u = (uint)u << 16; return v.f;
}

// ---------------------------------------------------------------------------
__global__ void zero_kernel(float* p, int n) {
    int i = blockIdx.x * blockDim.x + threadIdx.x;
    if (i < n) p[i] = 0.0f;
}

__global__ void hist_kernel(const int* __restrict__ dst, int* __restrict__ counts, int E) {
    int i = blockIdx.x * blockDim.x + threadIdx.x;
    if (i < E) atomicAdd(&counts[dst[i]], 1);
}

// --- 3-kernel multi-block scan -------------------------------------------
__global__ __launch_bounds__(1024) void scan1_kernel(const int* __restrict__ counts,
                                                     int* __restrict__ indptr,
                                                     int* __restrict__ bsum, int N) {
    __shared__ int sm[1024];
    int b = blockIdx.x;
    int i = b * 1024 + (int)threadIdx.x;
    int v = (i < N) ? counts[i] : 0;
    sm[threadIdx.x] = v;
    __syncthreads();
    for (int off = 1; off < 1024; off <<= 1) {
        int t = (threadIdx.x >= (unsigned)off) ? sm[threadIdx.x - off] : 0;
        __syncthreads();
        sm[threadIdx.x] += t;
        __syncthreads();
    }
    if (i < N) indptr[i + 1] = sm[threadIdx.x];
    if (threadIdx.x == 1023) bsum[b] = sm[1023];
}

__global__ void scan2_kernel(int* __restrict__ bsum, int nb) {
    int lane = threadIdx.x;
    int v = (lane < nb) ? bsum[lane] : 0;
    int orig = v;
    #pragma unroll
    for (int off = 1; off < 64; off <<= 1) {
        int t = __shfl_up(v, off, 64);
        if (lane >= off) v += t;
    }
    if (lane < nb) bsum[lane] = v - orig;   // exclusive
}

__global__ __launch_bounds__(1024) void scan3_kernel(const int* __restrict__ counts,
                                                     int* __restrict__ indptr,
                                                     int* __restrict__ cursor,
                                                     const int* __restrict__ bsum, int N) {
    int i = blockIdx.x * 1024 + (int)threadIdx.x;
    if (i == 0) indptr[0] = 0;
    if (i < N) {
        int incl = indptr[i + 1] + bsum[blockIdx.x];
        indptr[i + 1] = incl;
        cursor[i] = incl - counts[i];
    }
}

__global__ void fill_kernel(const int* __restrict__ src, const int* __restrict__ dst,
                            int* __restrict__ cursor, int* __restrict__ csr_src,
                            int* __restrict__ csr_dst, int E) {
    int i = blockIdx.x * blockDim.x + threadIdx.x;
    if (i < E) {
        int d = dst[i];
        int pos = atomicAdd(&cursor[d], 1);
        csr_src[pos] = src[i];
        csr_dst[pos] = d;
    }
}

// ---------------------------------------------------------------------------
// Pack W1 [1024,256] fp32 into bf16 MFMA-B fragment order.
__global__ void pack_w1(const float* __restrict__ W, ushort* __restrict__ Bp) {
    int o = blockIdx.x * blockDim.x + threadIdx.x;   // 0 .. 262143
    int j = o & 7;
    int lane = (o >> 3) & 63;
    int kchunk = (o >> 9) & 31;
    int ntile = o >> 14;
    int k = kchunk * 32 + (lane >> 4) * 8 + j;
    int n = ntile * 16 + (lane & 15);
    Bp[o] = f2bf(W[k * 256 + n]);
}

// Pack W2 [256,64] fp32 into bf16 MFMA-B fragment order (4 ntiles, 8 kchunks).
__global__ void pack_w2(const float* __restrict__ W, ushort* __restrict__ Bp) {
    int o = blockIdx.x * blockDim.x + threadIdx.x;   // 0 .. 16383
    int j = o & 7;
    int lane = (o >> 3) & 63;
    int kchunk = (o >> 9) & 7;
    int ntile = o >> 12;
    int k = kchunk * 32 + (lane >> 4) * 8 + j;
    int n = ntile * 16 + (lane & 15);
    Bp[o] = f2bf(W[k * 64 + n]);
}

// ---------------------------------------------------------------------------
// bf16 MFMA GEMM, layer 1: h1b[M,256](bf16) = A[M,1024](fp32) @ W1.
// Tile 128x256 (FULL N per block -> A staged exactly once). Double-buffered
// 8KB bf16 LDS; register prefetch issued AFTER the barrier so the loads are
// in flight during the MFMA phase (waitcnt lands at next iter's convert, not
// at the barrier drain). Epilogue fuses attention logits als1/ald1.
__global__ __launch_bounds__(256) void gemm1_mfma(const float* __restrict__ A,
                                                  const ushort* __restrict__ Bp,
                                                  ushort* __restrict__ C,
                                                  const float* __restrict__ asrc,
                                                  const float* __restrict__ adst,
                                                  float* __restrict__ als,
                                                  float* __restrict__ ald,
                                                  int M) {
    __shared__ __align__(16) ushort Atile[2][128 * 32];   // 2 x 8 KB
    const int K = 1024, N = 256;
    int tid = threadIdx.x;
    int lane = tid & 63;
    int w = tid >> 6;
    int wm = w >> 1, wn = w & 1;          // wave covers 64 rows x 128 cols
    int m0 = blockIdx.x * 128;

    const float* srow[4];
    int soff[4];
    #pragma unroll
    for (int l = 0; l < 4; ++l) {
        int slot = l * 256 + tid;
        int m = slot >> 3, hc = slot & 7;
        int c = hc >> 1;
        int row = m0 + m; if (row >= M) row = M - 1;
        srow[l] = A + (size_t)row * K + hc * 4;
        soff[l] = (m * 4 + (c ^ ((m >> 1) & 3))) * 8 + (hc & 1) * 4;
    }
    int afrag_off[4];
    #pragma unroll
    for (int mt = 0; mt < 4; ++mt) {
        int r = wm * 64 + mt * 16 + (lane & 15);
        int cq = lane >> 4;
        afrag_off[mt] = (r * 4 + (cq ^ ((r >> 1) & 3))) * 8;
    }
    const ushort* bbase[8];
    #pragma unroll
    for (int nt = 0; nt < 8; ++nt) {
        int ntile = wn * 8 + nt;
        bbase[nt] = Bp + ((size_t)(ntile * 32) * 64 + lane) * 8;
    }

    f32x4 acc[4][8] = {};
    float4 v[4];
    #pragma unroll
    for (int l = 0; l < 4; ++l) v[l] = *(const float4*)(srow[l]);

    for (int kc = 0; kc < 32; ++kc) {
        ushort* At = Atile[kc & 1];
        #pragma unroll
        for (int l = 0; l < 4; ++l) {
            ushort4 b;
            b.x = f2bf(v[l].x); b.y = f2bf(v[l].y);
            b.z = f2bf(v[l].z); b.w = f2bf(v[l].w);
            *(ushort4*)&At[soff[l]] = b;
        }
        __syncthreads();
        // prefetch next A chunk AFTER the barrier: in flight during MFMAs
        if (kc < 31) {
            #pragma unroll
            for (int l = 0; l < 4; ++l)
                v[l] = *(const float4*)(srow[l] + (kc + 1) * 32);
        }
        bf16x8 afr[4];
        #pragma unroll
        for (int mt = 0; mt < 4; ++mt)
            afr[mt] = *(const bf16x8*)&At[afrag_off[mt]];
        #pragma unroll
        for (int nt = 0; nt < 8; ++nt) {
            bf16x8 bfr = *(const bf16x8*)(bbase[nt] + (size_t)kc * 64 * 8);
            #pragma unroll
            for (int mt = 0; mt < 4; ++mt)
                acc[mt][nt] = __builtin_amdgcn_mfma_f32_16x16x32_bf16(afr[mt], bfr, acc[mt][nt], 0, 0, 0);
        }
    }

    // epilogue: C write (bf16) + fused attention logits (2 heads per wave)
    float a_s[8], a_d[8];
    #pragma unroll
    for (int nt = 0; nt < 8; ++nt) {
        int col = wn * 128 + nt * 16 + (lane & 15);   // head = col>>6
        a_s[nt] = asrc[col];
        a_d[nt] = adst[col];
    }
    #pragma unroll
    for (int mt = 0; mt < 4; ++mt) {
        #pragma unroll
        for (int nt = 0; nt < 8; ++nt) {
            int col = wn * 128 + nt * 16 + (lane & 15);
            #pragma unroll
            for (int r = 0; r < 4; ++r) {
                int row = m0 + wm * 64 + mt * 16 + (lane >> 4) * 4 + r;
                if (row < M) C[(size_t)row * N + col] = f2bf(acc[mt][nt][r]);
            }
        }
        #pragma unroll
        for (int hg = 0; hg < 2; ++hg) {         // head group: nt 4hg..4hg+3
            int head = wn * 2 + hg;
            #pragma unroll
            for (int r = 0; r < 4; ++r) {
                int row = m0 + wm * 64 + mt * 16 + (lane >> 4) * 4 + r;
                float s = 0.f, d = 0.f;
                #pragma unroll
                for (int q = 0; q < 4; ++q) {
                    float c = acc[mt][4 * hg + q][r];
                    s = fmaf(c, a_s[4 * hg + q], s);
                    d = fmaf(c, a_d[4 * hg + q], d);
                }
                #pragma unroll
                for (int off = 1; off < 16; off <<= 1) {
                    s += __shfl_xor(s, off, 64);
                    d += __shfl_xor(d, off, 64);
                }
                if ((lane & 15) == 0 && row < M) {
                    als[row * 4 + head] = s;
                    ald[row * 4 + head] = d;
                }
            }
        }
    }
}

// ---------------------------------------------------------------------------
// bf16 MFMA GEMM, layer 2: h2b[M,64](bf16) = x2b[M,256](bf16) @ W2.
// Epilogue fuses attention logits als2/ald2 (single head).
__global__ __launch_bounds__(256) void gemm2_mfma(const ushort* __restrict__ Ab,
                                                  const ushort* __restrict__ Bp,
                                                  ushort* __restrict__ C,
                                                  const float* __restrict__ asrc,
                                                  const float* __restrict__ adst,
                                                  float* __restrict__ als,
                                                  float* __restrict__ ald,
                                                  int M) {
    int tid = threadIdx.x;
    int lane = tid & 63;
    int w = tid >> 6;
    int m0 = blockIdx.x * 128 + w * 32;

    f32x4 acc[2][4] = {};
    #pragma unroll 2
    for (int kc = 0; kc < 8; ++kc) {
        bf16x8 afr[2];
        #pragma unroll
        for (int mt = 0; mt < 2; ++mt) {
            int r = m0 + mt * 16 + (lane & 15);
            if (r >= M) r = M - 1;
            afr[mt] = *(const bf16x8*)&Ab[(size_t)r * 256 + kc * 32 + (lane >> 4) * 8];
        }
        #pragma unroll
        for (int nt = 0; nt < 4; ++nt) {
            bf16x8 bfr = *(const bf16x8*)&Bp[((nt * 8 + kc) * 64 + lane) * 8];
            acc[0][nt] = __builtin_amdgcn_mfma_f32_16x16x32_bf16(afr[0], bfr, acc[0][nt], 0, 0, 0);
            acc[1][nt] = __builtin_amdgcn_mfma_f32_16x16x32_bf16(afr[1], bfr, acc[1][nt], 0, 0, 0);
        }
    }
    float a_s[4], a_d[4];
    #pragma unroll
    for (int nt = 0; nt < 4; ++nt) {
        a_s[nt] = asrc[nt * 16 + (lane & 15)];
        a_d[nt] = adst[nt * 16 + (lane & 15)];
    }
    #pragma unroll
    for (int mt = 0; mt < 2; ++mt) {
        #pragma unroll
        for (int nt = 0; nt < 4; ++nt) {
            int col = nt * 16 + (lane & 15);
            #pragma unroll
            for (int r = 0; r < 4; ++r) {
                int row = m0 + mt * 16 + (lane >> 4) * 4 + r;
                if (row < M) C[(size_t)row * 64 + col] = f2bf(acc[mt][nt][r]);
            }
        }
        #pragma unroll
        for (int r = 0; r < 4; ++r) {
            int row = m0 + mt * 16 + (lane >> 4) * 4 + r;
            float s = 0.f, d = 0.f;
            #pragma unroll
            for (int nt = 0; nt < 4; ++nt) {
                float c = acc[mt][nt][r];
                s = fmaf(c, a_s[nt], s);
                d = fmaf(c, a_d[nt], d);
            }
            #pragma unroll
            for (int off = 1; off < 16; off <<= 1) {
                s += __shfl_xor(s, off, 64);
                d += __shfl_xor(d, off, 64);
            }
            if ((lane & 15) == 0 && row < M) {
                als[row] = s;
                ald[row] = d;
            }
        }
    }
}

// ---------------------------------------------------------------------------
__device__ __forceinline__ float wave_reduce_sum(float v) {
    #pragma unroll
    for (int off = 32; off > 0; off >>= 1) v += __shfl_xor(v, off, 64);
    return v;
}

__device__ __forceinline__ float edge_w(float e) {
    e = (e > 0.f) ? e : NEG_SLOPE * e;
    return __expf(e);
}

// agg1: one node/block, 4 waves = 4 edge slices. Full 512-B row per wave.
__global__ __launch_bounds__(256) void agg1_kernel(const ushort* __restrict__ h,
                                                   const float* __restrict__ als,
                                                   const float* __restrict__ ald,
                                                   const int* __restrict__ indptr,
                                                   const int* __restrict__ csr_src,
                                                   const float* __restrict__ bias,
                                                   ushort* __restrict__ out, int N) {
    __shared__ float4 lacc[4][64];
    __shared__ float  lden[4][64];
    int n = blockIdx.x;
    int lane = threadIdx.x & 63;
    int wv = threadIdx.x >> 6;
    int hd = lane >> 4;
    int beg = indptr[n], end = indptr[n + 1];
    float ald_h = ald[n * 4 + hd];
    float4 acc = make_float4(0.f, 0.f, 0.f, 0.f);
    float den = 0.f;
    int p = beg + wv;
    for (; p + 4 < end; p += 8) {
        int s0 = csr_src[p], s1 = csr_src[p + 4];
        float w0 = edge_w(als[s0 * 4 + hd] + ald_h);
        float w1 = edge_w(als[s1 * 4 + hd] + ald_h);
        ushort4 a0 = *(const ushort4*)&h[(size_t)s0 * 256 + lane * 4];
        ushort4 a1 = *(const ushort4*)&h[(size_t)s1 * 256 + lane * 4];
        acc.x = fmaf(w0, bf2f(a0.x), fmaf(w1, bf2f(a1.x), acc.x));
        acc.y = fmaf(w0, bf2f(a0.y), fmaf(w1, bf2f(a1.y), acc.y));
        acc.z = fmaf(w0, bf2f(a0.z), fmaf(w1, bf2f(a1.z), acc.z));
        acc.w = fmaf(w0, bf2f(a0.w), fmaf(w1, bf2f(a1.w), acc.w));
        den += w0 + w1;
    }
    if (p < end) {
        int s0 = csr_src[p];
        float w0 = edge_w(als[s0 * 4 + hd] + ald_h);
        ushort4 a0 = *(const ushort4*)&h[(size_t)s0 * 256 + lane * 4];
        acc.x = fmaf(w0, bf2f(a0.x), acc.x);
        acc.y = fmaf(w0, bf2f(a0.y), acc.y);
        acc.z = fmaf(w0, bf2f(a0.z), acc.z);
        acc.w = fmaf(w0, bf2f(a0.w), acc.w);
        den += w0;
    }
    lacc[wv][lane] = acc;
    lden[wv][lane] = den;
    __syncthreads();
    if (wv == 0) {
        float4 a = lacc[0][lane];
        float4 a1 = lacc[1][lane], a2 = lacc[2][lane], a3 = lacc[3][lane];
        a.x += a1.x + a2.x + a3.x;
        a.y += a1.y + a2.y + a3.y;
        a.z += a1.z + a2.z + a3.z;
        a.w += a1.w + a2.w + a3.w;
        float d = lden[0][lane] + lden[1][lane] + lden[2][lane] + lden[3][lane];
        float4 bv = *(const float4*)&bias[lane * 4];
        float inv = 1.0f / d;
        float o0 = a.x * inv + bv.x, o1 = a.y * inv + bv.y;
        float o2 = a.z * inv + bv.z, o3 = a.w * inv + bv.w;
        o0 = (o0 > 0.f) ? o0 : (__expf(o0) - 1.0f);
        o1 = (o1 > 0.f) ? o1 : (__expf(o1) - 1.0f);
        o2 = (o2 > 0.f) ? o2 : (__expf(o2) - 1.0f);
        o3 = (o3 > 0.f) ? o3 : (__expf(o3) - 1.0f);
        ushort4 ob; ob.x = f2bf(o0); ob.y = f2bf(o1); ob.z = f2bf(o2); ob.w = f2bf(o3);
        *(ushort4*)&out[(size_t)n * 256 + lane * 4] = ob;
    }
}

// agg2: one node/block, 8 half-wave slices; 128-B row per half-wave.
__global__ __launch_bounds__(256) void agg2_kernel(const ushort* __restrict__ h,
                                                   const float* __restrict__ als,
                                                   const float* __restrict__ ald,
                                                   const int* __restrict__ indptr,
                                                   const int* __restrict__ csr_src,
                                                   const float* __restrict__ bias,
                                                   float* __restrict__ out, int N) {
    __shared__ float2 lacc[8][32];
    __shared__ float  lden[8][32];
    int n = blockIdx.x;
    int lane = threadIdx.x & 63;
    int wv = threadIdx.x >> 6;
    int sl = wv * 2 + (lane >> 5);    // slice 0..7
    int l32 = lane & 31;
    int beg = indptr[n], end = indptr[n + 1];
    float ald_n = ald[n];
    float2 acc = make_float2(0.f, 0.f);
    float den = 0.f;
    for (int p = beg + sl; p < end; p += 8) {
        int s = csr_src[p];
        float wt = edge_w(als[s] + ald_n);
        ushort2 hv = *(const ushort2*)&h[(size_t)s * 64 + l32 * 2];
        acc.x = fmaf(wt, bf2f(hv.x), acc.x);
        acc.y = fmaf(wt, bf2f(hv.y), acc.y);
        den += wt;
    }
    lacc[sl][l32] = acc;
    lden[sl][l32] = den;
    __syncthreads();
    if (threadIdx.x < 32) {
        int c = threadIdx.x;
        float2 a = make_float2(0.f, 0.f);
        float d = 0.f;
        #pragma unroll
        for (int s = 0; s < 8; ++s) {
            a.x += lacc[s][c].x; a.y += lacc[s][c].y;
            d += lden[s][c];
        }
        float inv = 1.0f / d;
        float o0 = a.x * inv + bias[c * 2];
        float o1 = a.y * inv + bias[c * 2 + 1];
        o0 = (o0 > 0.f) ? o0 : (__expf(o0) - 1.0f);
        o1 = (o1 > 0.f) ? o1 : (__expf(o1) - 1.0f);
        *(float2*)&out[(size_t)n * 64 + c * 2] = make_float2(o0, o1);
    }
}

// Fused mean-pool + FC: one block per graph (batch sorted => contiguous range).
__global__ __launch_bounds__(256) void pool_fc_kernel(const float* __restrict__ hfin,
                                                      const int* __restrict__ batch,
                                                      const float* __restrict__ fc_w,
                                                      const float* __restrict__ fc_b,
                                                      float* __restrict__ out, int N) {
    __shared__ float lacc[4][64];
    int g = blockIdx.x;
    int beg, end;
    {
        int lo = 0, hi = N;
        while (lo < hi) { int mid = (lo + hi) >> 1; if (batch[mid] < g) lo = mid + 1; else hi = mid; }
        beg = lo;
        lo = beg; hi = N;
        while (lo < hi) { int mid = (lo + hi) >> 1; if (batch[mid] < g + 1) lo = mid + 1; else hi = mid; }
        end = lo;
    }
    int lane = threadIdx.x & 63;
    int wv = threadIdx.x >> 6;
    float acc = 0.f;
    for (int n = beg + wv; n < end; n += 4)
        acc += hfin[(size_t)n * 64 + lane];
    lacc[wv][lane] = acc;
    __syncthreads();
    if (wv == 0) {
        float s = lacc[0][lane] + lacc[1][lane] + lacc[2][lane] + lacc[3][lane];
        float cnt = fmaxf((float)(end - beg), 1.0f);
        float pooled = s / cnt;
        float p0 = wave_reduce_sum(pooled * fc_w[lane * 2 + 0]);
        float p1 = wave_reduce_sum(pooled * fc_w[lane * 2 + 1]);
        if (lane == 0) {
            out[g * 2 + 0] = p0 + fc_b[0];
            out[g * 2 + 1] = p1 + fc_b[1];
        }
    }
}

// ---------------------------------------------------------------------------
extern "C" void kernel_launch(void* const* d_in, const int* in_sizes, int n_in,
                              void* d_out, int out_size, void* d_ws, size_t ws_size,
                              hipStream_t stream) {
    const float* x      = (const float*)d_in[0];
    const int*   ei     = (const int*)d_in[1];
    const int*   batch  = (const int*)d_in[2];
    const float* W1     = (const float*)d_in[3];
    const float* asrc1  = (const float*)d_in[4];
    const float* adst1  = (const float*)d_in[5];
    const float* b1     = (const float*)d_in[6];
    const float* W2     = (const float*)d_in[7];
    const float* asrc2  = (const float*)d_in[8];
    const float* adst2  = (const float*)d_in[9];
    const float* b2     = (const float*)d_in[10];
    const float* fc_w   = (const float*)d_in[11];
    const float* fc_b   = (const float*)d_in[12];
    float* out          = (float*)d_out;

    const int N = in_sizes[2];          // 50000
    const int E = in_sizes[1] / 2;      // 850000
    const int* src = ei;
    const int* dst = ei + E;

    float* ws = (float*)d_ws;
    int*    counts  = (int*)(ws + WS_COUNTS);
    int*    indptr  = (int*)(ws + WS_INDPTR);
    int*    cursor  = (int*)(ws + WS_CURSOR);
    int*    csr_src = (int*)(ws + WS_CSRSRC);
    int*    csr_dst = (int*)(ws + WS_CSRDST);
    int*    bsum    = (int*)(ws + WS_BSUM);
    float*  al_s1   = ws + WS_ALS1;
    float*  al_d1   = ws + WS_ALD1;
    float*  al_s2   = ws + WS_ALS2;
    float*  al_d2   = ws + WS_ALD2;
    ushort* bp      = (ushort*)(ws + WS_BP);
    ushort* bp2     = (ushort*)(ws + WS_BP2);
    ushort* h1b     = (ushort*)(ws + WS_H1B);
    ushort* x2b     = (ushort*)(ws + WS_X2B);
    ushort* h2b     = (ushort*)(ws + WS_H2B);
    float*  hfin    = ws + WS_HFIN;

    const int nb = (N + 1023) / 1024;   // scan blocks (<=64)

    // 1. zero counts; pack weights to bf16 fragment order
    zero_kernel<<<(WS_ZEROLEN + 255) / 256, 256, 0, stream>>>(ws, WS_ZEROLEN);
    pack_w1<<<(INDIM * F1) / 256, 256, 0, stream>>>(W1, bp);
    pack_w2<<<(F1 * HIDC) / 256, 256, 0, stream>>>(W2, bp2);
    // 2. CSR build (by dst)
    hist_kernel<<<(E + 255) / 256, 256, 0, stream>>>(dst, counts, E);
    scan1_kernel<<<nb, 1024, 0, stream>>>(counts, indptr, bsum, N);
    scan2_kernel<<<1, 64, 0, stream>>>(bsum, nb);
    scan3_kernel<<<nb, 1024, 0, stream>>>(counts, indptr, cursor, bsum, N);
    fill_kernel<<<(E + 255) / 256, 256, 0, stream>>>(src, dst, cursor, csr_src, csr_dst, E);
    // 3. layer 1 GEMM (128x256 tile, single A pass) -> h1b + fused att logits
    gemm1_mfma<<<(N + 127) / 128, 256, 0, stream>>>(
        x, bp, h1b, asrc1, adst1, al_s1, al_d1, N);
    // 4. aggregate (inline softmax weights) + bias + ELU -> x2b (bf16)
    agg1_kernel<<<N, 256, 0, stream>>>(h1b, al_s1, al_d1, indptr, csr_src, b1, x2b, N);
    // 5. layer 2 GEMM -> h2b (bf16) + fused att logits
    gemm2_mfma<<<(N + 127) / 128, 256, 0, stream>>>(
        x2b, bp2, h2b, asrc2, adst2, al_s2, al_d2, N);
    // 6. aggregate (inline softmax weights) + bias + ELU -> hfin (fp32)
    agg2_kernel<<<N, 256, 0, stream>>>(h2b, al_s2, al_d2, indptr, csr_src, b2, hfin, N);
    // 7. fused mean pool + FC
    pool_fc_kernel<<<NGRAPHS, 256, 0, stream>>>(hfin, batch, fc_w, fc_b, out, N);
}